// Round 1
// baseline (177.081 us; speedup 1.0000x reference)
//
#include <hip/hip_runtime.h>
#include <stdint.h>
#include <stddef.h>

typedef __bf16 bf16;
typedef __bf16 bf16x8 __attribute__((ext_vector_type(8)));
typedef float f32x4 __attribute__((ext_vector_type(4)));
typedef unsigned int uint32x2 __attribute__((ext_vector_type(2)));
typedef unsigned int uint32x4 __attribute__((ext_vector_type(4)));

typedef const __attribute__((address_space(1))) uint32_t GU32;
typedef __attribute__((address_space(3))) uint32_t LU32;

__device__ __forceinline__ f32x4 mfma16(bf16x8 a, bf16x8 b, f32x4 c) {
  return __builtin_amdgcn_mfma_f32_16x16x32_bf16(a, b, c, 0, 0, 0);
}
__device__ __forceinline__ void gload16(const void* g, void* l) {
  __builtin_amdgcn_global_load_lds((GU32*)g, (LU32*)l, 16, 0, 0);
}

// ---------------- prep: W_Q|W_K|W_V (f32 [2048][128]) -> Wct bf16 [384][2048] (transposed) ----
__global__ void k_prep(const float* __restrict__ Wq, const float* __restrict__ Wk,
                       const float* __restrict__ Wv, bf16* __restrict__ Wct) {
  int t = blockIdx.x * 256 + threadIdx.x;   // 786432 total
  int n = t >> 11, k = t & 2047;
  const float* s = (n < 128) ? Wq : (n < 256) ? Wk : Wv;
  Wct[t] = (bf16)s[k * 128 + (n & 127)];
}

// ---------------- projection GEMM + RoPE epilogue ----------------
// x f32 [16384][2048] @ Wct^T -> Q,K (RoPE, bf16 [b][s][128]) and Vt (bf16 [b][128][4096])
__global__ __launch_bounds__(256, 2) void k_proj(
    const float* __restrict__ x, const float* __restrict__ sint, const float* __restrict__ cost,
    const bf16* __restrict__ Wct, bf16* __restrict__ Qg, bf16* __restrict__ Kg,
    bf16* __restrict__ Vtg) {
  __shared__ __align__(16) uint8_t smem[65536];  // [2] x (A 16K | B 16K)
  const int tid = threadIdx.x;
  const int lane = tid & 63, w = tid >> 6;
  const int l15 = lane & 15, l16 = lane >> 4;
  const int mb = blockIdx.x / 3, nb = blockIdx.x % 3;
  const int wm = w >> 1, wn = w & 1;
  const int ar = tid >> 1, ah = tid & 1;

  f32x4 acc[4][4] = {};
  f32x4 areg[8];

  auto stageB = [&](int buf, int ks) {
    uint8_t* bbm = smem + buf * 32768 + 16384;
    int k0 = ks * 64;
#pragma unroll
    for (int i = 0; i < 4; ++i) {
      int L = i * 4096 + tid * 16;
      int n = L >> 7, cp = (L >> 4) & 7;
      int cc = cp ^ (n & 7);
      const uint8_t* src = (const uint8_t*)Wct + (((nb * 128 + n) * 2048 + k0 + cc * 8) << 1);
      gload16(src, bbm + i * 4096 + w * 1024);
    }
  };
  auto loadA = [&](int ks) {
    const f32x4* ap = (const f32x4*)(x + (mb * 128 + ar) * 2048 + ks * 64 + ah * 32);
#pragma unroll
    for (int i = 0; i < 8; ++i) areg[i] = ap[i];
  };
  auto writeA = [&](int buf) {
    uint8_t* ab = smem + buf * 32768;
#pragma unroll
    for (int i = 0; i < 4; ++i) {
      union { bf16 h[8]; uint32x4 u; } pk;
#pragma unroll
      for (int e = 0; e < 8; ++e) pk.h[e] = (bf16)areg[i * 2 + (e >> 2)][e & 3];
      int cc = (ah * 4 + i) ^ (ar & 7);
      *(uint32x4*)(ab + ar * 128 + cc * 16) = pk.u;
    }
  };
  auto computeS = [&](int buf) {
    uint8_t* ab = smem + buf * 32768;
    uint8_t* bbm = ab + 16384;
#pragma unroll
    for (int kk = 0; kk < 2; ++kk) {
      bf16x8 af[4], bv[4];
#pragma unroll
      for (int mt = 0; mt < 4; ++mt) {
        int ml = wm * 64 + mt * 16 + l15;
        af[mt] = *(const bf16x8*)(ab + ml * 128 + (((kk * 4 + l16) ^ (ml & 7)) << 4));
      }
#pragma unroll
      for (int nt = 0; nt < 4; ++nt) {
        int nl = wn * 64 + nt * 16 + l15;
        bv[nt] = *(const bf16x8*)(bbm + nl * 128 + (((kk * 4 + l16) ^ (nl & 7)) << 4));
      }
#pragma unroll
      for (int mt = 0; mt < 4; ++mt)
#pragma unroll
        for (int nt = 0; nt < 4; ++nt)
          acc[mt][nt] = mfma16(af[mt], bv[nt], acc[mt][nt]);
    }
  };

  stageB(0, 0);
  loadA(0);
  writeA(0);
  __syncthreads();
  for (int ks = 0; ks < 32; ++ks) {
    int cur = ks & 1;
    if (ks + 1 < 32) { stageB(cur ^ 1, ks + 1); loadA(ks + 1); }
    computeS(cur);
    if (ks + 1 < 32) writeA(cur ^ 1);
    __syncthreads();
  }

  // epilogue: RoPE for Q/K columns, transpose-store for V
#pragma unroll
  for (int mt = 0; mt < 4; ++mt) {
    int gm = mb * 128 + wm * 64 + mt * 16 + l16 * 4;
    int bb = gm >> 12, s0 = gm & 4095;
#pragma unroll
    for (int nt = 0; nt < 4; ++nt) {
      int jcol = nb * 128 + wn * 64 + nt * 16 + l15;
      f32x4 v = acc[mt][nt];
      if (jcol < 256) {
        int p = (jcol & 127) >> 1;
        bool even = ((jcol & 1) == 0);
#pragma unroll
        for (int r = 0; r < 4; ++r) {
          float pv = __shfl_xor(v[r], 1);
          int s = s0 + r;
          float cs = cost[s * 64 + p], sn = sint[s * 64 + p];
          float nv = even ? (v[r] * cs - pv * sn) : (v[r] * cs + pv * sn);
          bf16 hb = (bf16)nv;
          if (jcol < 128) Qg[((size_t)(bb << 12) + s) * 128 + jcol] = hb;
          else            Kg[((size_t)(bb << 12) + s) * 128 + jcol - 128] = hb;
        }
      } else {
        int d = jcol - 256;
        union { bf16 h[4]; uint32x2 u; } pk;
#pragma unroll
        for (int r = 0; r < 4; ++r) pk.h[r] = (bf16)v[r];
        *(uint32x2*)((uint8_t*)Vtg + (((size_t)(bb << 7) + d) * 4096 + s0) * 2) = pk.u;
      }
    }
  }
}

// ---------------- flash attention partials (KV-chunked causal) ----------------
// grid: 320 blocks = 4 batches x {j(0..31) x chunks(1+j/8)}; block = 4 waves x 32 q-rows
__global__ __launch_bounds__(256, 2) void k_attn(
    const bf16* __restrict__ Qg, const bf16* __restrict__ Kg, const bf16* __restrict__ Vtg,
    float* __restrict__ PO, float* __restrict__ ML) {
  __shared__ __align__(16) uint8_t smem[81920];  // [2] x (K 16K | V 16K) + 4 x P 4K
  const int tid = threadIdx.x;
  const int lane = tid & 63, w = tid >> 6;
  const int l15 = lane & 15, l16 = lane >> 4;

  int gid = blockIdx.x;
  int b = gid / 80, rr = gid % 80;
  int j, c;
  if (rr < 8)       { j = rr;                 c = 0; }
  else if (rr < 24) { j = 8 + ((rr - 8) >> 1);  c = (rr - 8) & 1; }
  else if (rr < 48) { j = 16 + (rr - 24) / 3;   c = (rr - 24) % 3; }
  else              { j = 24 + ((rr - 48) >> 2); c = (rr - 48) & 3; }

  const int q0w = j * 128 + w * 32;
  const int kv_lo = c * 1024;
  const int kv_hi = min((c + 1) * 1024, (j + 1) * 128);
  const int T = (kv_hi - kv_lo) >> 6;

  bf16x8 qf[2][4];
#pragma unroll
  for (int qt = 0; qt < 2; ++qt)
#pragma unroll
    for (int kk = 0; kk < 4; ++kk)
      qf[qt][kk] = *(const bf16x8*)(Qg + ((size_t)(b << 12) + q0w + qt * 16 + l15) * 128 + kk * 32 + l16 * 8);

  f32x4 o[2][8] = {};
  float m_r[2] = {-1e30f, -1e30f};
  float l_r[2] = {0.f, 0.f};
  uint8_t* pb = smem + 65536 + w * 4096;

  auto stage = [&](int t) {
    uint8_t* kb = smem + (t & 1) * 32768;
    uint8_t* vb = kb + 16384;
    int kv0 = kv_lo + t * 64;
#pragma unroll
    for (int i = 0; i < 4; ++i) {
      int L = i * 4096 + tid * 16;
      {
        int kv = L >> 8, cp = (L >> 4) & 15, cc = cp ^ (kv & 7);
        const uint8_t* src = (const uint8_t*)Kg + ((size_t)((b << 12) + kv0 + kv) << 8) + (cc << 4);
        gload16(src, kb + i * 4096 + w * 1024);
      }
      {
        int d = L >> 7, cp = (L >> 4) & 7, cc = cp ^ (d & 7);
        const uint8_t* src = (const uint8_t*)Vtg + ((size_t)(((b << 7) + d) << 12) + kv0 + (cc << 3)) * 2;
        gload16(src, vb + i * 4096 + w * 1024);
      }
    }
  };

  stage(0);
  __syncthreads();

  for (int t = 0; t < T; ++t) {
    if (t + 1 < T) stage(t + 1);
    const int kv0 = kv_lo + t * 64;
    if (kv0 <= q0w + 31) {
      uint8_t* kb = smem + (t & 1) * 32768;
      uint8_t* vb = kb + 16384;
      f32x4 sfr[4][2] = {};
#pragma unroll
      for (int kk = 0; kk < 4; ++kk) {
#pragma unroll
        for (int kvt = 0; kvt < 4; ++kvt) {
          int kvl = kvt * 16 + l15;
          bf16x8 kf = *(const bf16x8*)(kb + (kvl << 8) + (((kk * 4 + l16) ^ (kvl & 7)) << 4));
#pragma unroll
          for (int qt = 0; qt < 2; ++qt)
            sfr[kvt][qt] = mfma16(kf, qf[qt][kk], sfr[kvt][qt]);
        }
      }
      const bool need_mask = (kv0 + 63 > q0w);
      const float scale = 0.08838834764831845f;
#pragma unroll
      for (int qt = 0; qt < 2; ++qt) {
        const int q = q0w + qt * 16 + l15;
        float pvv[4][4];
        float tmax = -1e30f;
#pragma unroll
        for (int kvt = 0; kvt < 4; ++kvt)
#pragma unroll
          for (int r = 0; r < 4; ++r) {
            float sv = sfr[kvt][qt][r] * scale;
            if (need_mask) {
              int kv = kv0 + kvt * 16 + l16 * 4 + r;
              if (kv > q) sv = -1e30f;
            }
            pvv[kvt][r] = sv;
            tmax = fmaxf(tmax, sv);
          }
        tmax = fmaxf(tmax, __shfl_xor(tmax, 16));
        tmax = fmaxf(tmax, __shfl_xor(tmax, 32));
        float mnew = fmaxf(m_r[qt], tmax);
        float corr = __expf(m_r[qt] - mnew);
        m_r[qt] = mnew;
        float rs = 0.f;
#pragma unroll
        for (int kvt = 0; kvt < 4; ++kvt)
#pragma unroll
          for (int r = 0; r < 4; ++r) {
            float p = __expf(pvv[kvt][r] - mnew);
            pvv[kvt][r] = p;
            rs += p;
          }
        rs += __shfl_xor(rs, 16);
        rs += __shfl_xor(rs, 32);
        l_r[qt] = l_r[qt] * corr + rs;
        const int qrow = qt * 16 + l15;
#pragma unroll
        for (int kvt = 0; kvt < 4; ++kvt) {
          union { bf16 h[4]; uint32x2 u; } pk;
#pragma unroll
          for (int r = 0; r < 4; ++r) pk.h[r] = (bf16)pvv[kvt][r];
          int kv2 = kvt * 32 + l16 * 8;
          *(uint32x2*)(pb + qrow * 128 + ((((kv2 >> 4) ^ (qrow & 7)) << 4) | (kv2 & 15))) = pk.u;
        }
#pragma unroll
        for (int r = 0; r < 4; ++r) {
          float cr = __shfl(corr, l16 * 4 + r);
#pragma unroll
          for (int dt = 0; dt < 8; ++dt) o[qt][dt][r] *= cr;
        }
      }
      // PV
#pragma unroll
      for (int kvb = 0; kvb < 2; ++kvb) {
        bf16x8 pa[2];
#pragma unroll
        for (int qt = 0; qt < 2; ++qt) {
          int qrow = qt * 16 + l15;
          int kv2 = kvb * 64 + l16 * 16;
          pa[qt] = *(const bf16x8*)(pb + qrow * 128 + (((kv2 >> 4) ^ (qrow & 7)) << 4));
        }
#pragma unroll
        for (int dt = 0; dt < 8; ++dt) {
          int d = dt * 16 + l15;
          bf16x8 vf = *(const bf16x8*)(vb + (d << 7) + (((kvb * 4 + l16) ^ (d & 7)) << 4));
#pragma unroll
          for (int qt = 0; qt < 2; ++qt)
            o[qt][dt] = mfma16(pa[qt], vf, o[qt][dt]);
        }
      }
    }
    __syncthreads();
  }

  float* POb = PO + (size_t)((b * 32 + j) * 4 + c) * 16384;
#pragma unroll
  for (int qt = 0; qt < 2; ++qt)
#pragma unroll
    for (int dt = 0; dt < 8; ++dt)
#pragma unroll
      for (int r = 0; r < 4; ++r)
        POb[(w * 32 + qt * 16 + l16 * 4 + r) * 128 + dt * 16 + l15] = o[qt][dt][r];
  float* MLb = ML + (size_t)((b * 32 + j) * 4 + c) * 256;
  if (l16 == 0) {
#pragma unroll
    for (int qt = 0; qt < 2; ++qt) {
      MLb[w * 32 + qt * 16 + l15] = m_r[qt];
      MLb[128 + w * 32 + qt * 16 + l15] = l_r[qt];
    }
  }
}

// ---------------- combine partials ----------------
__global__ void k_combine(const float* __restrict__ PO, const float* __restrict__ ML,
                          float* __restrict__ out) {
  int blk = blockIdx.x;
  int b = blk >> 5, j = blk & 31;
  int nc = 1 + (j >> 3);
  int t = threadIdx.x;
  int q = t >> 1, half = t & 1;
  const float* MLb = ML + (size_t)(b * 32 + j) * 4 * 256;
  float mv[4], lv[4];
  float ms = -1e30f;
  for (int cc = 0; cc < nc; ++cc) {
    mv[cc] = MLb[cc * 256 + q];
    lv[cc] = MLb[cc * 256 + 128 + q];
    ms = fmaxf(ms, mv[cc]);
  }
  float wgt[4];
  float den = 0.f;
  for (int cc = 0; cc < nc; ++cc) { wgt[cc] = __expf(mv[cc] - ms); den += wgt[cc] * lv[cc]; }
  float inv = 1.f / den;
  const float* POb = PO + (size_t)(b * 32 + j) * 4 * 16384 + q * 128 + half * 64;
  float* ob = out + ((size_t)(b << 12) + j * 128 + q) * 128 + half * 64;
  for (int d = 0; d < 64; d += 4) {
    f32x4 a = {0.f, 0.f, 0.f, 0.f};
    for (int cc = 0; cc < nc; ++cc) {
      f32x4 v = *(const f32x4*)(POb + cc * 16384 + d);
      a += v * wgt[cc];
    }
    a *= inv;
    *(f32x4*)(ob + d) = a;
  }
}

extern "C" void kernel_launch(void* const* d_in, const int* in_sizes, int n_in,
                              void* d_out, int out_size, void* d_ws, size_t ws_size,
                              hipStream_t stream) {
  const float* x = (const float*)d_in[0];
  // d_in[1] = mask (causal; computed analytically)
  const float* sint = (const float*)d_in[2];
  const float* cost = (const float*)d_in[3];
  const float* Wq = (const float*)d_in[4];
  const float* Wk = (const float*)d_in[5];
  const float* Wv = (const float*)d_in[6];
  uint8_t* ws = (uint8_t*)d_ws;

  bf16* Wct = (bf16*)(ws + 0x0);        // 1.5 MB
  bf16* Qg  = (bf16*)(ws + 0x180000);   // 4 MB
  bf16* Kg  = (bf16*)(ws + 0x580000);   // 4 MB
  bf16* Vtg = (bf16*)(ws + 0x980000);   // 4 MB
  float* PO = (float*)(ws + 0xD80000);  // 32 MB
  float* ML = (float*)(ws + 0x2D80000); // 0.5 MB
  float* out = (float*)d_out;

  hipLaunchKernelGGL(k_prep, dim3(3072), dim3(256), 0, stream, Wq, Wk, Wv, Wct);
  hipLaunchKernelGGL(k_proj, dim3(384), dim3(256), 0, stream, x, sint, cost, Wct, Qg, Kg, Vtg);
  hipLaunchKernelGGL(k_attn, dim3(320), dim3(256), 0, stream, Qg, Kg, Vtg, PO, ML);
  hipLaunchKernelGGL(k_combine, dim3(128), dim3(256), 0, stream, PO, ML, out);
}

// Round 2
// 158.944 us; speedup vs baseline: 1.1141x; 1.1141x over previous
//
#include <hip/hip_runtime.h>
#include <stdint.h>
#include <stddef.h>

typedef __bf16 bf16;
typedef __bf16 bf16x8 __attribute__((ext_vector_type(8)));
typedef float f32x4 __attribute__((ext_vector_type(4)));
typedef unsigned int uint32x2 __attribute__((ext_vector_type(2)));
typedef unsigned int uint32x4 __attribute__((ext_vector_type(4)));

typedef const __attribute__((address_space(1))) uint32_t GU32;
typedef __attribute__((address_space(3))) uint32_t LU32;

__device__ __forceinline__ f32x4 mfma16(bf16x8 a, bf16x8 b, f32x4 c) {
  return __builtin_amdgcn_mfma_f32_16x16x32_bf16(a, b, c, 0, 0, 0);
}
__device__ __forceinline__ void gload16(const void* g, void* l) {
  __builtin_amdgcn_global_load_lds((GU32*)g, (LU32*)l, 16, 0, 0);
}

// ---------------- prep: W_Q|W_K|W_V (f32 [2048][128]) -> Wct bf16 [384][2048] (transposed) ----
__global__ void k_prep(const float* __restrict__ Wq, const float* __restrict__ Wk,
                       const float* __restrict__ Wv, bf16* __restrict__ Wct) {
  int t = blockIdx.x * 256 + threadIdx.x;   // 786432 total
  int n = t >> 11, k = t & 2047;
  const float* s = (n < 128) ? Wq : (n < 256) ? Wk : Wv;
  Wct[t] = (bf16)s[k * 128 + (n & 127)];
}

// ---------------- projection GEMM + RoPE epilogue ----------------
// x f32 [16384][2048] @ Wct^T -> Q,K (RoPE, bf16 [b][s][128]) and Vt (bf16 [b][128][4096])
// BM=64, full N=384; grid 256 blocks x 512 threads (8 waves, 48 cols each).
__global__ __launch_bounds__(512) void k_proj(
    const float* __restrict__ x, const float* __restrict__ sint, const float* __restrict__ cost,
    const bf16* __restrict__ Wct, bf16* __restrict__ Qg, bf16* __restrict__ Kg,
    bf16* __restrict__ Vtg) {
  __shared__ __align__(16) uint8_t smem[16384];  // 2 x 8KB A tiles (bf16, swizzled)
  const int tid = threadIdx.x;
  const int lane = tid & 63, w = tid >> 6;
  const int l15 = lane & 15, l16 = lane >> 4;
  const int mb = blockIdx.x;
  const int arow = tid >> 3, ac = tid & 7;   // staging: row 0..63, 8-float chunk 0..7

  f32x4 acc[4][3] = {};
  f32x4 aregA[2], aregB[2];

  const float* abase = x + (size_t)(mb * 64 + arow) * 2048 + ac * 8;

  auto loadA = [&](int ks, f32x4* r) {
    const f32x4* p = (const f32x4*)(abase + ks * 64);
    r[0] = p[0];
    r[1] = p[1];
  };
  auto writeA = [&](int buf, const f32x4* r) {
    union { bf16 h[8]; uint32x4 u; } pk;
#pragma unroll
    for (int e = 0; e < 8; ++e) pk.h[e] = (bf16)r[e >> 2][e & 3];
    *(uint32x4*)(smem + buf * 8192 + arow * 128 + ((ac ^ (arow & 7)) << 4)) = pk.u;
  };
  auto loadB = [&](int ks, bf16x8 bf[3][2]) {
#pragma unroll
    for (int nt = 0; nt < 3; ++nt)
#pragma unroll
      for (int h = 0; h < 2; ++h)
        bf[nt][h] = *(const bf16x8*)(Wct + (w * 48 + nt * 16 + l15) * 2048 + ks * 64 + h * 32 + l16 * 8);
  };
  auto compute = [&](int buf, bf16x8 bf[3][2]) {
    uint8_t* ab = smem + buf * 8192;
#pragma unroll
    for (int kk = 0; kk < 2; ++kk) {
      bf16x8 af[4];
#pragma unroll
      for (int mt = 0; mt < 4; ++mt) {
        int row = mt * 16 + l15;
        af[mt] = *(const bf16x8*)(ab + row * 128 + (((kk * 4 + l16) ^ (row & 7)) << 4));
      }
#pragma unroll
      for (int mt = 0; mt < 4; ++mt)
#pragma unroll
        for (int nt = 0; nt < 3; ++nt)
          acc[mt][nt] = mfma16(af[mt], bf[nt][kk], acc[mt][nt]);
    }
  };

  loadA(0, aregA);
  loadA(1, aregB);
  writeA(0, aregA);
  __syncthreads();
  for (int ks = 0; ks < 32; ks += 2) {
    // even step: buffer 0
    {
      if (ks + 2 < 32) loadA(ks + 2, aregA);
      bf16x8 bf[3][2];
      loadB(ks, bf);
      compute(0, bf);
      writeA(1, aregB);
      __syncthreads();
    }
    // odd step: buffer 1
    {
      if (ks + 3 < 32) loadA(ks + 3, aregB);
      bf16x8 bf[3][2];
      loadB(ks + 1, bf);
      compute(1, bf);
      if (ks + 2 < 32) writeA(0, aregA);
      __syncthreads();
    }
  }

  // epilogue: RoPE for Q/K columns, transpose-store for V
  const int bb = mb >> 6;
#pragma unroll
  for (int mt = 0; mt < 4; ++mt) {
    int gm = mb * 64 + mt * 16 + l16 * 4;
    int s0 = gm & 4095;
#pragma unroll
    for (int nt = 0; nt < 3; ++nt) {
      int jcol = w * 48 + nt * 16 + l15;
      f32x4 v = acc[mt][nt];
      if (jcol < 256) {
        int p = (jcol & 127) >> 1;
        bool even = ((jcol & 1) == 0);
#pragma unroll
        for (int r = 0; r < 4; ++r) {
          float pv = __shfl_xor(v[r], 1);
          int s = s0 + r;
          float cs = cost[s * 64 + p], sn = sint[s * 64 + p];
          float nv = even ? (v[r] * cs - pv * sn) : (v[r] * cs + pv * sn);
          bf16 hb = (bf16)nv;
          if (jcol < 128) Qg[((size_t)(bb << 12) + s) * 128 + jcol] = hb;
          else            Kg[((size_t)(bb << 12) + s) * 128 + jcol - 128] = hb;
        }
      } else {
        int d = jcol - 256;
        union { bf16 h[4]; uint32x2 u; } pk;
#pragma unroll
        for (int r = 0; r < 4; ++r) pk.h[r] = (bf16)v[r];
        *(uint32x2*)((uint8_t*)Vtg + (((size_t)(bb << 7) + d) * 4096 + s0) * 2) = pk.u;
      }
    }
  }
}

// ---------------- flash attention partials (KV-chunked causal) ----------------
// grid: 320 blocks = 4 batches x {j(0..31) x chunks(1+j/8)}; block = 4 waves x 32 q-rows
__global__ __launch_bounds__(256, 2) void k_attn(
    const bf16* __restrict__ Qg, const bf16* __restrict__ Kg, const bf16* __restrict__ Vtg,
    float* __restrict__ PO, float* __restrict__ ML) {
  __shared__ __align__(16) uint8_t smem[81920];  // [2] x (K 16K | V 16K) + 4 x P 4K
  const int tid = threadIdx.x;
  const int lane = tid & 63, w = tid >> 6;
  const int l15 = lane & 15, l16 = lane >> 4;

  int gid = blockIdx.x;
  int b = gid / 80, rr = gid % 80;
  int j, c;
  if (rr < 8)       { j = rr;                 c = 0; }
  else if (rr < 24) { j = 8 + ((rr - 8) >> 1);  c = (rr - 8) & 1; }
  else if (rr < 48) { j = 16 + (rr - 24) / 3;   c = (rr - 24) % 3; }
  else              { j = 24 + ((rr - 48) >> 2); c = (rr - 48) & 3; }

  const int q0w = j * 128 + w * 32;
  const int kv_lo = c * 1024;
  const int kv_hi = min((c + 1) * 1024, (j + 1) * 128);
  const int T = (kv_hi - kv_lo) >> 6;

  bf16x8 qf[2][4];
#pragma unroll
  for (int qt = 0; qt < 2; ++qt)
#pragma unroll
    for (int kk = 0; kk < 4; ++kk)
      qf[qt][kk] = *(const bf16x8*)(Qg + ((size_t)(b << 12) + q0w + qt * 16 + l15) * 128 + kk * 32 + l16 * 8);

  f32x4 o[2][8] = {};
  float m_r[2] = {-1e30f, -1e30f};
  float l_r[2] = {0.f, 0.f};
  uint8_t* pb = smem + 65536 + w * 4096;

  auto stage = [&](int t) {
    uint8_t* kb = smem + (t & 1) * 32768;
    uint8_t* vb = kb + 16384;
    int kv0 = kv_lo + t * 64;
#pragma unroll
    for (int i = 0; i < 4; ++i) {
      int L = i * 4096 + tid * 16;
      {
        int kv = L >> 8, cp = (L >> 4) & 15, cc = cp ^ (kv & 7);
        const uint8_t* src = (const uint8_t*)Kg + ((size_t)((b << 12) + kv0 + kv) << 8) + (cc << 4);
        gload16(src, kb + i * 4096 + w * 1024);
      }
      {
        int d = L >> 7, cp = (L >> 4) & 7, cc = cp ^ (d & 7);
        const uint8_t* src = (const uint8_t*)Vtg + ((size_t)(((b << 7) + d) << 12) + kv0 + (cc << 3)) * 2;
        gload16(src, vb + i * 4096 + w * 1024);
      }
    }
  };

  stage(0);
  __syncthreads();

  for (int t = 0; t < T; ++t) {
    if (t + 1 < T) stage(t + 1);
    const int kv0 = kv_lo + t * 64;
    if (kv0 <= q0w + 31) {
      uint8_t* kb = smem + (t & 1) * 32768;
      uint8_t* vb = kb + 16384;
      f32x4 sfr[4][2] = {};
#pragma unroll
      for (int kk = 0; kk < 4; ++kk) {
#pragma unroll
        for (int kvt = 0; kvt < 4; ++kvt) {
          int kvl = kvt * 16 + l15;
          bf16x8 kf = *(const bf16x8*)(kb + (kvl << 8) + (((kk * 4 + l16) ^ (kvl & 7)) << 4));
#pragma unroll
          for (int qt = 0; qt < 2; ++qt)
            sfr[kvt][qt] = mfma16(kf, qf[qt][kk], sfr[kvt][qt]);
        }
      }
      const bool need_mask = (kv0 + 63 > q0w);
      const float scale = 0.08838834764831845f;
#pragma unroll
      for (int qt = 0; qt < 2; ++qt) {
        const int q = q0w + qt * 16 + l15;
        float pvv[4][4];
        float tmax = -1e30f;
#pragma unroll
        for (int kvt = 0; kvt < 4; ++kvt)
#pragma unroll
          for (int r = 0; r < 4; ++r) {
            float sv = sfr[kvt][qt][r] * scale;
            if (need_mask) {
              int kv = kv0 + kvt * 16 + l16 * 4 + r;
              if (kv > q) sv = -1e30f;
            }
            pvv[kvt][r] = sv;
            tmax = fmaxf(tmax, sv);
          }
        tmax = fmaxf(tmax, __shfl_xor(tmax, 16));
        tmax = fmaxf(tmax, __shfl_xor(tmax, 32));
        float mnew = fmaxf(m_r[qt], tmax);
        float corr = __expf(m_r[qt] - mnew);
        m_r[qt] = mnew;
        float rs = 0.f;
#pragma unroll
        for (int kvt = 0; kvt < 4; ++kvt)
#pragma unroll
          for (int r = 0; r < 4; ++r) {
            float p = __expf(pvv[kvt][r] - mnew);
            pvv[kvt][r] = p;
            rs += p;
          }
        rs += __shfl_xor(rs, 16);
        rs += __shfl_xor(rs, 32);
        l_r[qt] = l_r[qt] * corr + rs;
        const int qrow = qt * 16 + l15;
#pragma unroll
        for (int kvt = 0; kvt < 4; ++kvt) {
          union { bf16 h[4]; uint32x2 u; } pk;
#pragma unroll
          for (int r = 0; r < 4; ++r) pk.h[r] = (bf16)pvv[kvt][r];
          int kv2 = kvt * 32 + l16 * 8;
          *(uint32x2*)(pb + qrow * 128 + ((((kv2 >> 4) ^ (qrow & 7)) << 4) | (kv2 & 15))) = pk.u;
        }
#pragma unroll
        for (int r = 0; r < 4; ++r) {
          float cr = __shfl(corr, l16 * 4 + r);
#pragma unroll
          for (int dt = 0; dt < 8; ++dt) o[qt][dt][r] *= cr;
        }
      }
      // PV
#pragma unroll
      for (int kvb = 0; kvb < 2; ++kvb) {
        bf16x8 pa[2];
#pragma unroll
        for (int qt = 0; qt < 2; ++qt) {
          int qrow = qt * 16 + l15;
          int kv2 = kvb * 64 + l16 * 16;
          pa[qt] = *(const bf16x8*)(pb + qrow * 128 + (((kv2 >> 4) ^ (qrow & 7)) << 4));
        }
#pragma unroll
        for (int dt = 0; dt < 8; ++dt) {
          int d = dt * 16 + l15;
          bf16x8 vf = *(const bf16x8*)(vb + (d << 7) + (((kvb * 4 + l16) ^ (d & 7)) << 4));
#pragma unroll
          for (int qt = 0; qt < 2; ++qt)
            o[qt][dt] = mfma16(pa[qt], vf, o[qt][dt]);
        }
      }
    }
    __syncthreads();
  }

  float* POb = PO + (size_t)((b * 32 + j) * 4 + c) * 16384;
#pragma unroll
  for (int qt = 0; qt < 2; ++qt)
#pragma unroll
    for (int dt = 0; dt < 8; ++dt)
#pragma unroll
      for (int r = 0; r < 4; ++r)
        POb[(w * 32 + qt * 16 + l16 * 4 + r) * 128 + dt * 16 + l15] = o[qt][dt][r];
  float* MLb = ML + (size_t)((b * 32 + j) * 4 + c) * 256;
  if (l16 == 0) {
#pragma unroll
    for (int qt = 0; qt < 2; ++qt) {
      MLb[w * 32 + qt * 16 + l15] = m_r[qt];
      MLb[128 + w * 32 + qt * 16 + l15] = l_r[qt];
    }
  }
}

// ---------------- combine partials ----------------
__global__ void k_combine(const float* __restrict__ PO, const float* __restrict__ ML,
                          float* __restrict__ out) {
  int blk = blockIdx.x;
  int b = blk >> 5, j = blk & 31;
  int nc = 1 + (j >> 3);
  int t = threadIdx.x;
  int q = t >> 1, half = t & 1;
  const float* MLb = ML + (size_t)(b * 32 + j) * 4 * 256;
  float mv[4], lv[4];
  float ms = -1e30f;
  for (int cc = 0; cc < nc; ++cc) {
    mv[cc] = MLb[cc * 256 + q];
    lv[cc] = MLb[cc * 256 + 128 + q];
    ms = fmaxf(ms, mv[cc]);
  }
  float wgt[4];
  float den = 0.f;
  for (int cc = 0; cc < nc; ++cc) { wgt[cc] = __expf(mv[cc] - ms); den += wgt[cc] * lv[cc]; }
  float inv = 1.f / den;
  const float* POb = PO + (size_t)(b * 32 + j) * 4 * 16384 + q * 128 + half * 64;
  float* ob = out + ((size_t)(b << 12) + j * 128 + q) * 128 + half * 64;
  for (int d = 0; d < 64; d += 4) {
    f32x4 a = {0.f, 0.f, 0.f, 0.f};
    for (int cc = 0; cc < nc; ++cc) {
      f32x4 v = *(const f32x4*)(POb + cc * 16384 + d);
      a += v * wgt[cc];
    }
    a *= inv;
    *(f32x4*)(ob + d) = a;
  }
}

extern "C" void kernel_launch(void* const* d_in, const int* in_sizes, int n_in,
                              void* d_out, int out_size, void* d_ws, size_t ws_size,
                              hipStream_t stream) {
  const float* x = (const float*)d_in[0];
  // d_in[1] = mask (causal; computed analytically)
  const float* sint = (const float*)d_in[2];
  const float* cost = (const float*)d_in[3];
  const float* Wq = (const float*)d_in[4];
  const float* Wk = (const float*)d_in[5];
  const float* Wv = (const float*)d_in[6];
  uint8_t* ws = (uint8_t*)d_ws;

  bf16* Wct = (bf16*)(ws + 0x0);        // 1.5 MB
  bf16* Qg  = (bf16*)(ws + 0x180000);   // 4 MB
  bf16* Kg  = (bf16*)(ws + 0x580000);   // 4 MB
  bf16* Vtg = (bf16*)(ws + 0x980000);   // 4 MB
  float* PO = (float*)(ws + 0xD80000);  // 32 MB
  float* ML = (float*)(ws + 0x2D80000); // 0.5 MB
  float* out = (float*)d_out;

  hipLaunchKernelGGL(k_prep, dim3(3072), dim3(256), 0, stream, Wq, Wk, Wv, Wct);
  hipLaunchKernelGGL(k_proj, dim3(256), dim3(512), 0, stream, x, sint, cost, Wct, Qg, Kg, Vtg);
  hipLaunchKernelGGL(k_attn, dim3(320), dim3(256), 0, stream, Qg, Kg, Vtg, PO, ML);
  hipLaunchKernelGGL(k_combine, dim3(128), dim3(256), 0, stream, PO, ML, out);
}

// Round 3
// 152.878 us; speedup vs baseline: 1.1583x; 1.0397x over previous
//
#include <hip/hip_runtime.h>
#include <stdint.h>
#include <stddef.h>

typedef __bf16 bf16;
typedef __bf16 bf16x8 __attribute__((ext_vector_type(8)));
typedef float f32x4 __attribute__((ext_vector_type(4)));
typedef unsigned int uint32x2 __attribute__((ext_vector_type(2)));
typedef unsigned int uint32x4 __attribute__((ext_vector_type(4)));

typedef const __attribute__((address_space(1))) uint32_t GU32;
typedef __attribute__((address_space(3))) uint32_t LU32;

__device__ __forceinline__ f32x4 mfma16(bf16x8 a, bf16x8 b, f32x4 c) {
  return __builtin_amdgcn_mfma_f32_16x16x32_bf16(a, b, c, 0, 0, 0);
}
__device__ __forceinline__ void gload16(const void* g, void* l) {
  __builtin_amdgcn_global_load_lds((GU32*)g, (LU32*)l, 16, 0, 0);
}

// ---------------- prep: W_Q|W_K|W_V (f32 [2048][128]) -> Wct bf16 [384][2048] (transposed) ----
__global__ void k_prep(const float* __restrict__ Wq, const float* __restrict__ Wk,
                       const float* __restrict__ Wv, bf16* __restrict__ Wct) {
  int t = blockIdx.x * 256 + threadIdx.x;   // 786432 total
  int n = t >> 11, k = t & 2047;
  const float* s = (n < 128) ? Wq : (n < 256) ? Wk : Wv;
  Wct[t] = (bf16)s[k * 128 + (n & 127)];
}

// ---------------- projection GEMM + RoPE epilogue ----------------
// x f32 [16384][2048] @ Wct^T -> Q,K (RoPE, bf16 [b][s][128]) and Vt (bf16 [b][128][4096])
// BM=64, BN=128; grid 768 = 256 M x 3 N; 256 threads (4 waves 2x2); 3 blocks/CU.
__global__ __launch_bounds__(256, 3) void k_proj(
    const float* __restrict__ x, const float* __restrict__ sint, const float* __restrict__ cost,
    const bf16* __restrict__ Wct, bf16* __restrict__ Qg, bf16* __restrict__ Kg,
    bf16* __restrict__ Vtg) {
  __shared__ __align__(16) uint8_t smem[49152];  // 2 x (A 8KB | B 16KB), swizzled bf16
  const int tid = threadIdx.x;
  const int lane = tid & 63, w = tid >> 6;
  const int l15 = lane & 15, l16 = lane >> 4;
  const int nb = blockIdx.x % 3, mb = blockIdx.x / 3;
  const int wm = w >> 1, wn = w & 1;
  const int arow = tid >> 2, aj = tid & 3;   // A staging: row 0..63, 16-float group 0..3

  f32x4 acc[2][4] = {};
  f32x4 areg[4];

  const float* abase = x + (size_t)(mb * 64 + arow) * 2048 + aj * 16;

  auto stageB = [&](int buf, int ks) {
    uint8_t* bbm = smem + buf * 24576 + 8192;
    int k0 = ks * 64;
#pragma unroll
    for (int i = 0; i < 4; ++i) {
      int L = i * 4096 + tid * 16;
      int n = L >> 7, cp = (L >> 4) & 7;
      int cc = cp ^ (n & 7);
      const uint8_t* src = (const uint8_t*)Wct + (((nb * 128 + n) * 2048 + k0 + cc * 8) << 1);
      gload16(src, bbm + i * 4096 + w * 1024);
    }
  };
  auto loadA = [&](int ks) {
    const f32x4* p = (const f32x4*)(abase + ks * 64);
#pragma unroll
    for (int i = 0; i < 4; ++i) areg[i] = p[i];
  };
  auto writeA = [&](int buf) {
    uint8_t* ab = smem + buf * 24576;
#pragma unroll
    for (int h = 0; h < 2; ++h) {
      union { bf16 v[8]; uint32x4 u; } pk;
#pragma unroll
      for (int e = 0; e < 8; ++e) pk.v[e] = (bf16)areg[h * 2 + (e >> 2)][e & 3];
      int c = aj * 2 + h;
      *(uint32x4*)(ab + arow * 128 + (((c ^ (arow & 7)) & 7) << 4)) = pk.u;
    }
  };
  auto compute = [&](int buf) {
    uint8_t* ab = smem + buf * 24576;
    uint8_t* bbm = ab + 8192;
#pragma unroll
    for (int kk = 0; kk < 2; ++kk) {
      bf16x8 af[2], bv[4];
#pragma unroll
      for (int mt = 0; mt < 2; ++mt) {
        int ml = wm * 32 + mt * 16 + l15;
        af[mt] = *(const bf16x8*)(ab + ml * 128 + (((kk * 4 + l16) ^ (ml & 7)) << 4));
      }
#pragma unroll
      for (int nt = 0; nt < 4; ++nt) {
        int nl = wn * 64 + nt * 16 + l15;
        bv[nt] = *(const bf16x8*)(bbm + nl * 128 + (((kk * 4 + l16) ^ (nl & 7)) << 4));
      }
#pragma unroll
      for (int mt = 0; mt < 2; ++mt)
#pragma unroll
        for (int nt = 0; nt < 4; ++nt)
          acc[mt][nt] = mfma16(af[mt], bv[nt], acc[mt][nt]);
    }
  };

  stageB(0, 0);
  loadA(0);
  writeA(0);
  __syncthreads();
  for (int ks = 0; ks < 32; ++ks) {
    int cur = ks & 1;
    if (ks + 1 < 32) { stageB(cur ^ 1, ks + 1); loadA(ks + 1); }
    compute(cur);
    if (ks + 1 < 32) writeA(cur ^ 1);
    __syncthreads();
  }

  // epilogue: RoPE for Q/K columns, transpose-store for V
  const int bb = mb >> 6;
#pragma unroll
  for (int mt = 0; mt < 2; ++mt) {
    int gm = mb * 64 + wm * 32 + mt * 16 + l16 * 4;
    int s0 = gm & 4095;
#pragma unroll
    for (int nt = 0; nt < 4; ++nt) {
      int jcol = nb * 128 + wn * 64 + nt * 16 + l15;
      f32x4 v = acc[mt][nt];
      if (jcol < 256) {
        int p = (jcol & 127) >> 1;
        bool even = ((jcol & 1) == 0);
#pragma unroll
        for (int r = 0; r < 4; ++r) {
          float pv = __shfl_xor(v[r], 1);
          int s = s0 + r;
          float cs = cost[s * 64 + p], sn = sint[s * 64 + p];
          float nv = even ? (v[r] * cs - pv * sn) : (v[r] * cs + pv * sn);
          bf16 hb = (bf16)nv;
          if (jcol < 128) Qg[((size_t)(bb << 12) + s) * 128 + jcol] = hb;
          else            Kg[((size_t)(bb << 12) + s) * 128 + jcol - 128] = hb;
        }
      } else {
        int d = jcol - 256;
        union { bf16 h[4]; uint32x2 u; } pk;
#pragma unroll
        for (int r = 0; r < 4; ++r) pk.h[r] = (bf16)v[r];
        *(uint32x2*)((uint8_t*)Vtg + (((size_t)(bb << 7) + d) * 4096 + s0) * 2) = pk.u;
      }
    }
  }
}

// ---------------- flash attention partials (KV-chunked causal) ----------------
// grid: 320 blocks = 4 batches x {j(0..31) x chunks(1+j/8)}; block = 4 waves x 32 q-rows
__global__ __launch_bounds__(256, 2) void k_attn(
    const bf16* __restrict__ Qg, const bf16* __restrict__ Kg, const bf16* __restrict__ Vtg,
    float* __restrict__ PO, float* __restrict__ ML) {
  __shared__ __align__(16) uint8_t smem[81920];  // [2] x (K 16K | V 16K) + 4 x P 4K
  const int tid = threadIdx.x;
  const int lane = tid & 63, w = tid >> 6;
  const int l15 = lane & 15, l16 = lane >> 4;

  int gid = blockIdx.x;
  int b = gid / 80, rr = gid % 80;
  int j, c;
  if (rr < 8)       { j = rr;                 c = 0; }
  else if (rr < 24) { j = 8 + ((rr - 8) >> 1);  c = (rr - 8) & 1; }
  else if (rr < 48) { j = 16 + (rr - 24) / 3;   c = (rr - 24) % 3; }
  else              { j = 24 + ((rr - 48) >> 2); c = (rr - 48) & 3; }

  const int q0w = j * 128 + w * 32;
  const int kv_lo = c * 1024;
  const int kv_hi = min((c + 1) * 1024, (j + 1) * 128);
  const int T = (kv_hi - kv_lo) >> 6;

  bf16x8 qf[2][4];
#pragma unroll
  for (int qt = 0; qt < 2; ++qt)
#pragma unroll
    for (int kk = 0; kk < 4; ++kk)
      qf[qt][kk] = *(const bf16x8*)(Qg + ((size_t)(b << 12) + q0w + qt * 16 + l15) * 128 + kk * 32 + l16 * 8);

  f32x4 o[2][8] = {};
  float m_r[2] = {-1e30f, -1e30f};
  float l_r[2] = {0.f, 0.f};
  uint8_t* pb = smem + 65536 + w * 4096;

  auto stage = [&](int t) {
    uint8_t* kb = smem + (t & 1) * 32768;
    uint8_t* vb = kb + 16384;
    int kv0 = kv_lo + t * 64;
#pragma unroll
    for (int i = 0; i < 4; ++i) {
      int L = i * 4096 + tid * 16;
      {
        int kv = L >> 8, cp = (L >> 4) & 15, cc = cp ^ (kv & 7);
        const uint8_t* src = (const uint8_t*)Kg + ((size_t)((b << 12) + kv0 + kv) << 8) + (cc << 4);
        gload16(src, kb + i * 4096 + w * 1024);
      }
      {
        int d = L >> 7, cp = (L >> 4) & 7, cc = cp ^ (d & 7);
        const uint8_t* src = (const uint8_t*)Vtg + ((size_t)(((b << 7) + d) << 12) + kv0 + (cc << 3)) * 2;
        gload16(src, vb + i * 4096 + w * 1024);
      }
    }
  };

  stage(0);
  __syncthreads();

  for (int t = 0; t < T; ++t) {
    if (t + 1 < T) stage(t + 1);
    const int kv0 = kv_lo + t * 64;
    if (kv0 <= q0w + 31) {
      uint8_t* kb = smem + (t & 1) * 32768;
      uint8_t* vb = kb + 16384;
      f32x4 sfr[4][2] = {};
#pragma unroll
      for (int kk = 0; kk < 4; ++kk) {
#pragma unroll
        for (int kvt = 0; kvt < 4; ++kvt) {
          int kvl = kvt * 16 + l15;
          bf16x8 kf = *(const bf16x8*)(kb + (kvl << 8) + (((kk * 4 + l16) ^ (kvl & 7)) << 4));
#pragma unroll
          for (int qt = 0; qt < 2; ++qt)
            sfr[kvt][qt] = mfma16(kf, qf[qt][kk], sfr[kvt][qt]);
        }
      }
      const bool need_mask = (kv0 + 63 > q0w);
      const float scale = 0.08838834764831845f;
#pragma unroll
      for (int qt = 0; qt < 2; ++qt) {
        const int q = q0w + qt * 16 + l15;
        float pvv[4][4];
        float tmax = -1e30f;
#pragma unroll
        for (int kvt = 0; kvt < 4; ++kvt)
#pragma unroll
          for (int r = 0; r < 4; ++r) {
            float sv = sfr[kvt][qt][r] * scale;
            if (need_mask) {
              int kv = kv0 + kvt * 16 + l16 * 4 + r;
              if (kv > q) sv = -1e30f;
            }
            pvv[kvt][r] = sv;
            tmax = fmaxf(tmax, sv);
          }
        tmax = fmaxf(tmax, __shfl_xor(tmax, 16));
        tmax = fmaxf(tmax, __shfl_xor(tmax, 32));
        float mnew = fmaxf(m_r[qt], tmax);
        float corr = __expf(m_r[qt] - mnew);
        m_r[qt] = mnew;
        float rs = 0.f;
#pragma unroll
        for (int kvt = 0; kvt < 4; ++kvt)
#pragma unroll
          for (int r = 0; r < 4; ++r) {
            float p = __expf(pvv[kvt][r] - mnew);
            pvv[kvt][r] = p;
            rs += p;
          }
        rs += __shfl_xor(rs, 16);
        rs += __shfl_xor(rs, 32);
        l_r[qt] = l_r[qt] * corr + rs;
        const int qrow = qt * 16 + l15;
#pragma unroll
        for (int kvt = 0; kvt < 4; ++kvt) {
          union { bf16 h[4]; uint32x2 u; } pk;
#pragma unroll
          for (int r = 0; r < 4; ++r) pk.h[r] = (bf16)pvv[kvt][r];
          int kv2 = kvt * 32 + l16 * 8;
          *(uint32x2*)(pb + qrow * 128 + ((((kv2 >> 4) ^ (qrow & 7)) << 4) | (kv2 & 15))) = pk.u;
        }
#pragma unroll
        for (int r = 0; r < 4; ++r) {
          float cr = __shfl(corr, l16 * 4 + r);
#pragma unroll
          for (int dt = 0; dt < 8; ++dt) o[qt][dt][r] *= cr;
        }
      }
      // PV
#pragma unroll
      for (int kvb = 0; kvb < 2; ++kvb) {
        bf16x8 pa[2];
#pragma unroll
        for (int qt = 0; qt < 2; ++qt) {
          int qrow = qt * 16 + l15;
          int kv2 = kvb * 64 + l16 * 16;
          pa[qt] = *(const bf16x8*)(pb + qrow * 128 + (((kv2 >> 4) ^ (qrow & 7)) << 4));
        }
#pragma unroll
        for (int dt = 0; dt < 8; ++dt) {
          int d = dt * 16 + l15;
          bf16x8 vf = *(const bf16x8*)(vb + (d << 7) + (((kvb * 4 + l16) ^ (d & 7)) << 4));
#pragma unroll
          for (int qt = 0; qt < 2; ++qt)
            o[qt][dt] = mfma16(pa[qt], vf, o[qt][dt]);
        }
      }
    }
    __syncthreads();
  }

  float* POb = PO + (size_t)((b * 32 + j) * 4 + c) * 16384;
#pragma unroll
  for (int qt = 0; qt < 2; ++qt)
#pragma unroll
    for (int dt = 0; dt < 8; ++dt)
#pragma unroll
      for (int r = 0; r < 4; ++r)
        POb[(w * 32 + qt * 16 + l16 * 4 + r) * 128 + dt * 16 + l15] = o[qt][dt][r];
  float* MLb = ML + (size_t)((b * 32 + j) * 4 + c) * 256;
  if (l16 == 0) {
#pragma unroll
    for (int qt = 0; qt < 2; ++qt) {
      MLb[w * 32 + qt * 16 + l15] = m_r[qt];
      MLb[128 + w * 32 + qt * 16 + l15] = l_r[qt];
    }
  }
}

// ---------------- combine partials ----------------
__global__ void k_combine(const float* __restrict__ PO, const float* __restrict__ ML,
                          float* __restrict__ out) {
  int blk = blockIdx.x;
  int b = blk >> 5, j = blk & 31;
  int nc = 1 + (j >> 3);
  int t = threadIdx.x;
  int q = t >> 1, half = t & 1;
  const float* MLb = ML + (size_t)(b * 32 + j) * 4 * 256;
  float mv[4], lv[4];
  float ms = -1e30f;
  for (int cc = 0; cc < nc; ++cc) {
    mv[cc] = MLb[cc * 256 + q];
    lv[cc] = MLb[cc * 256 + 128 + q];
    ms = fmaxf(ms, mv[cc]);
  }
  float wgt[4];
  float den = 0.f;
  for (int cc = 0; cc < nc; ++cc) { wgt[cc] = __expf(mv[cc] - ms); den += wgt[cc] * lv[cc]; }
  float inv = 1.f / den;
  const float* POb = PO + (size_t)(b * 32 + j) * 4 * 16384 + q * 128 + half * 64;
  float* ob = out + ((size_t)(b << 12) + j * 128 + q) * 128 + half * 64;
  for (int d = 0; d < 64; d += 4) {
    f32x4 a = {0.f, 0.f, 0.f, 0.f};
    for (int cc = 0; cc < nc; ++cc) {
      f32x4 v = *(const f32x4*)(POb + cc * 16384 + d);
      a += v * wgt[cc];
    }
    a *= inv;
    *(f32x4*)(ob + d) = a;
  }
}

extern "C" void kernel_launch(void* const* d_in, const int* in_sizes, int n_in,
                              void* d_out, int out_size, void* d_ws, size_t ws_size,
                              hipStream_t stream) {
  const float* x = (const float*)d_in[0];
  // d_in[1] = mask (causal; computed analytically)
  const float* sint = (const float*)d_in[2];
  const float* cost = (const float*)d_in[3];
  const float* Wq = (const float*)d_in[4];
  const float* Wk = (const float*)d_in[5];
  const float* Wv = (const float*)d_in[6];
  uint8_t* ws = (uint8_t*)d_ws;

  bf16* Wct = (bf16*)(ws + 0x0);        // 1.5 MB
  bf16* Qg  = (bf16*)(ws + 0x180000);   // 4 MB
  bf16* Kg  = (bf16*)(ws + 0x580000);   // 4 MB
  bf16* Vtg = (bf16*)(ws + 0x980000);   // 4 MB
  float* PO = (float*)(ws + 0xD80000);  // 32 MB
  float* ML = (float*)(ws + 0x2D80000); // 0.5 MB
  float* out = (float*)d_out;

  hipLaunchKernelGGL(k_prep, dim3(3072), dim3(256), 0, stream, Wq, Wk, Wv, Wct);
  hipLaunchKernelGGL(k_proj, dim3(768), dim3(256), 0, stream, x, sint, cost, Wct, Qg, Kg, Vtg);
  hipLaunchKernelGGL(k_attn, dim3(320), dim3(256), 0, stream, Qg, Kg, Vtg, PO, ML);
  hipLaunchKernelGGL(k_combine, dim3(128), dim3(256), 0, stream, PO, ML, out);
}

// Round 4
// 140.678 us; speedup vs baseline: 1.2588x; 1.0867x over previous
//
#include <hip/hip_runtime.h>
#include <stdint.h>
#include <stddef.h>

typedef __bf16 bf16;
typedef __bf16 bf16x8 __attribute__((ext_vector_type(8)));
typedef float f32x4 __attribute__((ext_vector_type(4)));
typedef unsigned int uint32x2 __attribute__((ext_vector_type(2)));
typedef unsigned int uint32x4 __attribute__((ext_vector_type(4)));

typedef const __attribute__((address_space(1))) uint32_t GU32;
typedef __attribute__((address_space(3))) uint32_t LU32;

__device__ __forceinline__ f32x4 mfma16(bf16x8 a, bf16x8 b, f32x4 c) {
  return __builtin_amdgcn_mfma_f32_16x16x32_bf16(a, b, c, 0, 0, 0);
}
__device__ __forceinline__ void gload16(const void* g, void* l) {
  __builtin_amdgcn_global_load_lds((GU32*)g, (LU32*)l, 16, 0, 0);
}

// ---------------- prep: W_Q|W_K|W_V (f32 [2048][128]) -> Wct bf16 [384][2048] ----
// Coalesced via 64x64 LDS transpose tiles. Grid 192 = 3 matrices x 32 k-tiles x 2 n-tiles.
__global__ __launch_bounds__(256) void k_prep(const float* __restrict__ Wq,
                                              const float* __restrict__ Wk,
                                              const float* __restrict__ Wv,
                                              bf16* __restrict__ Wct) {
  __shared__ float tile[64][65];
  const int tid = threadIdx.x;
  const int widx = blockIdx.x >> 6, rem = blockIdx.x & 63;
  const int k0 = (rem >> 1) * 64, n0 = (rem & 1) * 64;
  const float* W = (widx == 0) ? Wq : (widx == 1) ? Wk : Wv;
  const int rg = tid >> 4, cq = tid & 15;
#pragma unroll
  for (int i = 0; i < 4; ++i) {
    int krow = i * 16 + rg;
    f32x4 v = *(const f32x4*)(W + (size_t)(k0 + krow) * 128 + n0 + cq * 4);
#pragma unroll
    for (int j = 0; j < 4; ++j) tile[krow][cq * 4 + j] = v[j];
  }
  __syncthreads();
#pragma unroll
  for (int i = 0; i < 4; ++i) {
    int nrow = i * 16 + rg;
    union { bf16 h[4]; uint32x2 u; } pk;
#pragma unroll
    for (int j = 0; j < 4; ++j) pk.h[j] = (bf16)tile[cq * 4 + j][nrow];
    *(uint32x2*)(Wct + (size_t)(widx * 128 + n0 + nrow) * 2048 + k0 + cq * 4) = pk.u;
  }
}

// ---------------- projection GEMM + RoPE epilogue ----------------
// x f32 [16384][2048] @ Wct^T -> Q,K (RoPE, bf16 [b][s][128]) and Vt (bf16 [b][128][4096])
// BM=64, BN=192; grid 512 = 256 M x 2 N (XCD-swizzled); 256 threads (4 waves 2x2); 2 blocks/CU.
__global__ __launch_bounds__(256, 2) void k_proj(
    const float* __restrict__ x, const float* __restrict__ sint, const float* __restrict__ cost,
    const bf16* __restrict__ Wct, bf16* __restrict__ Qg, bf16* __restrict__ Kg,
    bf16* __restrict__ Vtg) {
  __shared__ __align__(16) uint8_t smem[65536];  // 2 x (A 8KB | B 24KB), swizzled bf16
  const int tid = threadIdx.x;
  const int lane = tid & 63, w = tid >> 6;
  const int l15 = lane & 15, l16 = lane >> 4;
  // bijective XCD swizzle: 512 blocks, 64 consecutive logical blocks per XCD;
  // nb fastest so the two N-passes sharing an A-tile stay on one XCD.
  const int logical = (blockIdx.x & 7) * 64 + (blockIdx.x >> 3);
  const int nb = logical & 1, mb = logical >> 1;
  const int wm = w >> 1, wn = w & 1;
  const int arow = tid >> 2, aj = tid & 3;   // A staging: row 0..63, 16-float group 0..3

  f32x4 acc[2][6] = {};
  f32x4 areg[4];

  const float* abase = x + (size_t)(mb * 64 + arow) * 2048 + aj * 16;

  auto stageB = [&](int buf, int ks) {
    uint8_t* bbm = smem + buf * 32768 + 8192;
    int k0 = ks * 64;
#pragma unroll
    for (int i = 0; i < 6; ++i) {
      int L = i * 4096 + tid * 16;
      int n = L >> 7, cp = (L >> 4) & 7;
      int cc = cp ^ (n & 7);
      const uint8_t* src = (const uint8_t*)Wct + (((size_t)(nb * 192 + n) * 2048 + k0 + cc * 8) << 1);
      gload16(src, bbm + i * 4096 + w * 1024);
    }
  };
  auto loadA = [&](int ks) {
    const f32x4* p = (const f32x4*)(abase + ks * 64);
#pragma unroll
    for (int i = 0; i < 4; ++i) areg[i] = p[i];
  };
  auto writeA = [&](int buf) {
    uint8_t* ab = smem + buf * 32768;
#pragma unroll
    for (int h = 0; h < 2; ++h) {
      union { bf16 v[8]; uint32x4 u; } pk;
#pragma unroll
      for (int e = 0; e < 8; ++e) pk.v[e] = (bf16)areg[h * 2 + (e >> 2)][e & 3];
      int c = aj * 2 + h;
      *(uint32x4*)(ab + arow * 128 + (((c ^ (arow & 7)) & 7) << 4)) = pk.u;
    }
  };
  auto compute = [&](int buf) {
    uint8_t* ab = smem + buf * 32768;
    uint8_t* bbm = ab + 8192;
#pragma unroll
    for (int kk = 0; kk < 2; ++kk) {
      bf16x8 af[2], bv[6];
#pragma unroll
      for (int mt = 0; mt < 2; ++mt) {
        int ml = wm * 32 + mt * 16 + l15;
        af[mt] = *(const bf16x8*)(ab + ml * 128 + (((kk * 4 + l16) ^ (ml & 7)) << 4));
      }
#pragma unroll
      for (int nt = 0; nt < 6; ++nt) {
        int nl = wn * 96 + nt * 16 + l15;
        bv[nt] = *(const bf16x8*)(bbm + nl * 128 + (((kk * 4 + l16) ^ (nl & 7)) << 4));
      }
#pragma unroll
      for (int mt = 0; mt < 2; ++mt)
#pragma unroll
        for (int nt = 0; nt < 6; ++nt)
          acc[mt][nt] = mfma16(af[mt], bv[nt], acc[mt][nt]);
    }
  };

  stageB(0, 0);
  loadA(0);
  writeA(0);
  __syncthreads();
  for (int ks = 0; ks < 32; ++ks) {
    int cur = ks & 1;
    if (ks + 1 < 32) { stageB(cur ^ 1, ks + 1); loadA(ks + 1); }
    compute(cur);
    if (ks + 1 < 32) writeA(cur ^ 1);
    __syncthreads();
  }

  // epilogue: RoPE for Q/K columns, transpose-store for V
#pragma unroll
  for (int mt = 0; mt < 2; ++mt) {
    int gm = mb * 64 + wm * 32 + mt * 16 + l16 * 4;
    int bb = gm >> 12, s0 = gm & 4095;
#pragma unroll
    for (int nt = 0; nt < 6; ++nt) {
      int jcol = nb * 192 + wn * 96 + nt * 16 + l15;
      f32x4 v = acc[mt][nt];
      if (jcol < 256) {
        int p = (jcol & 127) >> 1;
        bool even = ((jcol & 1) == 0);
#pragma unroll
        for (int r = 0; r < 4; ++r) {
          float pv = __shfl_xor(v[r], 1);
          int s = s0 + r;
          float cs = cost[s * 64 + p], sn = sint[s * 64 + p];
          float nv = even ? (v[r] * cs - pv * sn) : (v[r] * cs + pv * sn);
          bf16 hb = (bf16)nv;
          if (jcol < 128) Qg[((size_t)(bb << 12) + s) * 128 + jcol] = hb;
          else            Kg[((size_t)(bb << 12) + s) * 128 + jcol - 128] = hb;
        }
      } else {
        int d = jcol - 256;
        union { bf16 h[4]; uint32x2 u; } pk;
#pragma unroll
        for (int r = 0; r < 4; ++r) pk.h[r] = (bf16)v[r];
        *(uint32x2*)((uint8_t*)Vtg + (((size_t)(bb << 7) + d) * 4096 + s0) * 2) = pk.u;
      }
    }
  }
}

// ---------------- flash attention partials (KV-chunked causal) ----------------
// grid: 320 blocks = 4 batches x {j(0..31) x chunks(1+j/8)}; block = 4 waves x 32 q-rows
__global__ __launch_bounds__(256, 2) void k_attn(
    const bf16* __restrict__ Qg, const bf16* __restrict__ Kg, const bf16* __restrict__ Vtg,
    float* __restrict__ PO, float* __restrict__ ML) {
  __shared__ __align__(16) uint8_t smem[81920];  // [2] x (K 16K | V 16K) + 4 x P 4K
  const int tid = threadIdx.x;
  const int lane = tid & 63, w = tid >> 6;
  const int l15 = lane & 15, l16 = lane >> 4;

  int gid = blockIdx.x;
  int b = gid / 80, rr = gid % 80;
  int j, c;
  if (rr < 8)       { j = rr;                 c = 0; }
  else if (rr < 24) { j = 8 + ((rr - 8) >> 1);  c = (rr - 8) & 1; }
  else if (rr < 48) { j = 16 + (rr - 24) / 3;   c = (rr - 24) % 3; }
  else              { j = 24 + ((rr - 48) >> 2); c = (rr - 48) & 3; }

  const int q0w = j * 128 + w * 32;
  const int kv_lo = c * 1024;
  const int kv_hi = min((c + 1) * 1024, (j + 1) * 128);
  const int T = (kv_hi - kv_lo) >> 6;

  bf16x8 qf[2][4];
#pragma unroll
  for (int qt = 0; qt < 2; ++qt)
#pragma unroll
    for (int kk = 0; kk < 4; ++kk)
      qf[qt][kk] = *(const bf16x8*)(Qg + ((size_t)(b << 12) + q0w + qt * 16 + l15) * 128 + kk * 32 + l16 * 8);

  f32x4 o[2][8] = {};
  float m_r[2] = {-1e30f, -1e30f};
  float l_r[2] = {0.f, 0.f};
  uint8_t* pb = smem + 65536 + w * 4096;

  auto stage = [&](int t) {
    uint8_t* kb = smem + (t & 1) * 32768;
    uint8_t* vb = kb + 16384;
    int kv0 = kv_lo + t * 64;
#pragma unroll
    for (int i = 0; i < 4; ++i) {
      int L = i * 4096 + tid * 16;
      {
        int kv = L >> 8, cp = (L >> 4) & 15, cc = cp ^ (kv & 7);
        const uint8_t* src = (const uint8_t*)Kg + ((size_t)((b << 12) + kv0 + kv) << 8) + (cc << 4);
        gload16(src, kb + i * 4096 + w * 1024);
      }
      {
        int d = L >> 7, cp = (L >> 4) & 7, cc = cp ^ (d & 7);
        const uint8_t* src = (const uint8_t*)Vtg + ((size_t)(((b << 7) + d) << 12) + kv0 + (cc << 3)) * 2;
        gload16(src, vb + i * 4096 + w * 1024);
      }
    }
  };

  stage(0);
  __syncthreads();

  for (int t = 0; t < T; ++t) {
    if (t + 1 < T) stage(t + 1);
    const int kv0 = kv_lo + t * 64;
    if (kv0 <= q0w + 31) {
      uint8_t* kb = smem + (t & 1) * 32768;
      uint8_t* vb = kb + 16384;
      f32x4 sfr[4][2] = {};
#pragma unroll
      for (int kk = 0; kk < 4; ++kk) {
#pragma unroll
        for (int kvt = 0; kvt < 4; ++kvt) {
          int kvl = kvt * 16 + l15;
          bf16x8 kf = *(const bf16x8*)(kb + (kvl << 8) + (((kk * 4 + l16) ^ (kvl & 7)) << 4));
#pragma unroll
          for (int qt = 0; qt < 2; ++qt)
            sfr[kvt][qt] = mfma16(kf, qf[qt][kk], sfr[kvt][qt]);
        }
      }
      const bool need_mask = (kv0 + 63 > q0w);
      const float scale = 0.08838834764831845f;
#pragma unroll
      for (int qt = 0; qt < 2; ++qt) {
        const int q = q0w + qt * 16 + l15;
        float pvv[4][4];
        float tmax = -1e30f;
#pragma unroll
        for (int kvt = 0; kvt < 4; ++kvt)
#pragma unroll
          for (int r = 0; r < 4; ++r) {
            float sv = sfr[kvt][qt][r] * scale;
            if (need_mask) {
              int kv = kv0 + kvt * 16 + l16 * 4 + r;
              if (kv > q) sv = -1e30f;
            }
            pvv[kvt][r] = sv;
            tmax = fmaxf(tmax, sv);
          }
        tmax = fmaxf(tmax, __shfl_xor(tmax, 16));
        tmax = fmaxf(tmax, __shfl_xor(tmax, 32));
        float mnew = fmaxf(m_r[qt], tmax);
        float corr = __expf(m_r[qt] - mnew);
        m_r[qt] = mnew;
        float rs = 0.f;
#pragma unroll
        for (int kvt = 0; kvt < 4; ++kvt)
#pragma unroll
          for (int r = 0; r < 4; ++r) {
            float p = __expf(pvv[kvt][r] - mnew);
            pvv[kvt][r] = p;
            rs += p;
          }
        rs += __shfl_xor(rs, 16);
        rs += __shfl_xor(rs, 32);
        l_r[qt] = l_r[qt] * corr + rs;
        const int qrow = qt * 16 + l15;
#pragma unroll
        for (int kvt = 0; kvt < 4; ++kvt) {
          union { bf16 h[4]; uint32x2 u; } pk;
#pragma unroll
          for (int r = 0; r < 4; ++r) pk.h[r] = (bf16)pvv[kvt][r];
          int kv2 = kvt * 32 + l16 * 8;
          *(uint32x2*)(pb + qrow * 128 + ((((kv2 >> 4) ^ (qrow & 7)) << 4) | (kv2 & 15))) = pk.u;
        }
#pragma unroll
        for (int r = 0; r < 4; ++r) {
          float cr = __shfl(corr, l16 * 4 + r);
#pragma unroll
          for (int dt = 0; dt < 8; ++dt) o[qt][dt][r] *= cr;
        }
      }
      // PV
#pragma unroll
      for (int kvb = 0; kvb < 2; ++kvb) {
        bf16x8 pa[2];
#pragma unroll
        for (int qt = 0; qt < 2; ++qt) {
          int qrow = qt * 16 + l15;
          int kv2 = kvb * 64 + l16 * 16;
          pa[qt] = *(const bf16x8*)(pb + qrow * 128 + (((kv2 >> 4) ^ (qrow & 7)) << 4));
        }
#pragma unroll
        for (int dt = 0; dt < 8; ++dt) {
          int d = dt * 16 + l15;
          bf16x8 vf = *(const bf16x8*)(vb + (d << 7) + (((kvb * 4 + l16) ^ (d & 7)) << 4));
#pragma unroll
          for (int qt = 0; qt < 2; ++qt)
            o[qt][dt] = mfma16(pa[qt], vf, o[qt][dt]);
        }
      }
    }
    __syncthreads();
  }

  float* POb = PO + (size_t)((b * 32 + j) * 4 + c) * 16384;
#pragma unroll
  for (int qt = 0; qt < 2; ++qt)
#pragma unroll
    for (int dt = 0; dt < 8; ++dt)
#pragma unroll
      for (int r = 0; r < 4; ++r)
        POb[(w * 32 + qt * 16 + l16 * 4 + r) * 128 + dt * 16 + l15] = o[qt][dt][r];
  float* MLb = ML + (size_t)((b * 32 + j) * 4 + c) * 256;
  if (l16 == 0) {
#pragma unroll
    for (int qt = 0; qt < 2; ++qt) {
      MLb[w * 32 + qt * 16 + l15] = m_r[qt];
      MLb[128 + w * 32 + qt * 16 + l15] = l_r[qt];
    }
  }
}

// ---------------- combine partials ----------------
__global__ void k_combine(const float* __restrict__ PO, const float* __restrict__ ML,
                          float* __restrict__ out) {
  int blk = blockIdx.x;
  int b = blk >> 5, j = blk & 31;
  int nc = 1 + (j >> 3);
  int t = threadIdx.x;
  int q = t >> 1, half = t & 1;
  const float* MLb = ML + (size_t)(b * 32 + j) * 4 * 256;
  float mv[4], lv[4];
  float ms = -1e30f;
  for (int cc = 0; cc < nc; ++cc) {
    mv[cc] = MLb[cc * 256 + q];
    lv[cc] = MLb[cc * 256 + 128 + q];
    ms = fmaxf(ms, mv[cc]);
  }
  float wgt[4];
  float den = 0.f;
  for (int cc = 0; cc < nc; ++cc) { wgt[cc] = __expf(mv[cc] - ms); den += wgt[cc] * lv[cc]; }
  float inv = 1.f / den;
  const float* POb = PO + (size_t)(b * 32 + j) * 4 * 16384 + q * 128 + half * 64;
  float* ob = out + ((size_t)(b << 12) + j * 128 + q) * 128 + half * 64;
  for (int d = 0; d < 64; d += 4) {
    f32x4 a = {0.f, 0.f, 0.f, 0.f};
    for (int cc = 0; cc < nc; ++cc) {
      f32x4 v = *(const f32x4*)(POb + cc * 16384 + d);
      a += v * wgt[cc];
    }
    a *= inv;
    *(f32x4*)(ob + d) = a;
  }
}

extern "C" void kernel_launch(void* const* d_in, const int* in_sizes, int n_in,
                              void* d_out, int out_size, void* d_ws, size_t ws_size,
                              hipStream_t stream) {
  const float* x = (const float*)d_in[0];
  // d_in[1] = mask (causal; computed analytically)
  const float* sint = (const float*)d_in[2];
  const float* cost = (const float*)d_in[3];
  const float* Wq = (const float*)d_in[4];
  const float* Wk = (const float*)d_in[5];
  const float* Wv = (const float*)d_in[6];
  uint8_t* ws = (uint8_t*)d_ws;

  bf16* Wct = (bf16*)(ws + 0x0);        // 1.5 MB
  bf16* Qg  = (bf16*)(ws + 0x180000);   // 4 MB
  bf16* Kg  = (bf16*)(ws + 0x580000);   // 4 MB
  bf16* Vtg = (bf16*)(ws + 0x980000);   // 4 MB
  float* PO = (float*)(ws + 0xD80000);  // 32 MB
  float* ML = (float*)(ws + 0x2D80000); // 0.5 MB
  float* out = (float*)d_out;

  hipLaunchKernelGGL(k_prep, dim3(192), dim3(256), 0, stream, Wq, Wk, Wv, Wct);
  hipLaunchKernelGGL(k_proj, dim3(512), dim3(256), 0, stream, x, sint, cost, Wct, Qg, Kg, Vtg);
  hipLaunchKernelGGL(k_attn, dim3(320), dim3(256), 0, stream, Qg, Kg, Vtg, PO, ML);
  hipLaunchKernelGGL(k_combine, dim3(128), dim3(256), 0, stream, PO, ML, out);
}

// Round 5
// 132.195 us; speedup vs baseline: 1.3395x; 1.0642x over previous
//
#include <hip/hip_runtime.h>
#include <stdint.h>
#include <stddef.h>

typedef __bf16 bf16;
typedef __bf16 bf16x8 __attribute__((ext_vector_type(8)));
typedef float f32x4 __attribute__((ext_vector_type(4)));
typedef unsigned int uint32x2 __attribute__((ext_vector_type(2)));
typedef unsigned int uint32x4 __attribute__((ext_vector_type(4)));

typedef const __attribute__((address_space(1))) uint32_t GU32;
typedef __attribute__((address_space(3))) uint32_t LU32;

__device__ __forceinline__ f32x4 mfma16(bf16x8 a, bf16x8 b, f32x4 c) {
  return __builtin_amdgcn_mfma_f32_16x16x32_bf16(a, b, c, 0, 0, 0);
}
__device__ __forceinline__ void gload16(const void* g, void* l) {
  __builtin_amdgcn_global_load_lds((GU32*)g, (LU32*)l, 16, 0, 0);
}

// ---------------- prep: W_Q|W_K|W_V (f32 [2048][128]) -> Wct bf16 [384][2048] ----
// Coalesced via 64x64 LDS transpose tiles. Grid 192 = 3 matrices x 32 k-tiles x 2 n-tiles.
__global__ __launch_bounds__(256) void k_prep(const float* __restrict__ Wq,
                                              const float* __restrict__ Wk,
                                              const float* __restrict__ Wv,
                                              bf16* __restrict__ Wct) {
  __shared__ float tile[64][65];
  const int tid = threadIdx.x;
  const int widx = blockIdx.x >> 6, rem = blockIdx.x & 63;
  const int k0 = (rem >> 1) * 64, n0 = (rem & 1) * 64;
  const float* W = (widx == 0) ? Wq : (widx == 1) ? Wk : Wv;
  const int rg = tid >> 4, cq = tid & 15;
#pragma unroll
  for (int i = 0; i < 4; ++i) {
    int krow = i * 16 + rg;
    f32x4 v = *(const f32x4*)(W + (size_t)(k0 + krow) * 128 + n0 + cq * 4);
#pragma unroll
    for (int j = 0; j < 4; ++j) tile[krow][cq * 4 + j] = v[j];
  }
  __syncthreads();
#pragma unroll
  for (int i = 0; i < 4; ++i) {
    int nrow = i * 16 + rg;
    union { bf16 h[4]; uint32x2 u; } pk;
#pragma unroll
    for (int j = 0; j < 4; ++j) pk.h[j] = (bf16)tile[cq * 4 + j][nrow];
    *(uint32x2*)(Wct + (size_t)(widx * 128 + n0 + nrow) * 2048 + k0 + cq * 4) = pk.u;
  }
}

// ---------------- projection GEMM + RoPE epilogue ----------------
// x f32 [16384][2048] @ Wct^T -> Q,K (RoPE, bf16 [b][s][128]) and Vt (bf16 [b][128][4096])
// BM=64, BN=192; grid 512 = 256 M x 2 N (XCD-swizzled); 256 threads (4 waves 2x2).
// Counted-vmcnt pipeline: loads issued 1-2 iters ahead; never drain vmcnt in the loop.
__global__ __launch_bounds__(256, 2) void k_proj(
    const float* __restrict__ x, const float* __restrict__ sint, const float* __restrict__ cost,
    const bf16* __restrict__ Wct, bf16* __restrict__ Qg, bf16* __restrict__ Kg,
    bf16* __restrict__ Vtg) {
  __shared__ __align__(16) uint8_t smem[65536];  // 2 x (A 8KB | B 24KB), swizzled bf16
  const int tid = threadIdx.x;
  const int lane = tid & 63, w = tid >> 6;
  const int l15 = lane & 15, l16 = lane >> 4;
  const int logical = (blockIdx.x & 7) * 64 + (blockIdx.x >> 3);
  const int nb = logical & 1, mb = logical >> 1;
  const int wm = w >> 1, wn = w & 1;
  const int arow = tid >> 2, aj = tid & 3;   // A staging: row 0..63, 16-float group 0..3

  f32x4 acc[2][6] = {};
  f32x4 regA[4], regB[4];

  const float* abase = x + (size_t)(mb * 64 + arow) * 2048 + aj * 16;

  auto stageB = [&](int buf, int ks) {
    uint8_t* bbm = smem + buf * 32768 + 8192;
    int k0 = ks * 64;
#pragma unroll
    for (int i = 0; i < 6; ++i) {
      int L = i * 4096 + tid * 16;
      int n = L >> 7, cp = (L >> 4) & 7;
      int cc = cp ^ (n & 7);
      const uint8_t* src = (const uint8_t*)Wct + (((size_t)(nb * 192 + n) * 2048 + k0 + cc * 8) << 1);
      gload16(src, bbm + i * 4096 + w * 1024);
    }
  };
  auto loadA = [&](int ks, f32x4* r) {
    const f32x4* p = (const f32x4*)(abase + ks * 64);
#pragma unroll
    for (int i = 0; i < 4; ++i) r[i] = p[i];
  };
  auto writeA = [&](int buf, const f32x4* r) {
    uint8_t* ab = smem + buf * 32768;
#pragma unroll
    for (int h = 0; h < 2; ++h) {
      union { bf16 v[8]; uint32x4 u; } pk;
#pragma unroll
      for (int e = 0; e < 8; ++e) pk.v[e] = (bf16)r[h * 2 + (e >> 2)][e & 3];
      int c = aj * 2 + h;
      *(uint32x4*)(ab + arow * 128 + (((c ^ (arow & 7)) & 7) << 4)) = pk.u;
    }
  };
  auto compute = [&](int buf) {
    uint8_t* ab = smem + buf * 32768;
    uint8_t* bbm = ab + 8192;
    bf16x8 af[2][2], bv[2][6];
#pragma unroll
    for (int kk = 0; kk < 2; ++kk) {
#pragma unroll
      for (int mt = 0; mt < 2; ++mt) {
        int ml = wm * 32 + mt * 16 + l15;
        af[kk][mt] = *(const bf16x8*)(ab + ml * 128 + (((kk * 4 + l16) ^ (ml & 7)) << 4));
      }
#pragma unroll
      for (int nt = 0; nt < 6; ++nt) {
        int nl = wn * 96 + nt * 16 + l15;
        bv[kk][nt] = *(const bf16x8*)(bbm + nl * 128 + (((kk * 4 + l16) ^ (nl & 7)) << 4));
      }
    }
    __builtin_amdgcn_s_setprio(1);
#pragma unroll
    for (int kk = 0; kk < 2; ++kk)
#pragma unroll
      for (int mt = 0; mt < 2; ++mt)
#pragma unroll
        for (int nt = 0; nt < 6; ++nt)
          acc[mt][nt] = mfma16(af[kk][mt], bv[kk][nt], acc[mt][nt]);
    __builtin_amdgcn_s_setprio(0);
  };

  // prologue: fill LDS[0] with ks=0; regB <- A(1); leave loadA(1) in flight
  loadA(0, regA);
  stageB(0, 0);
  loadA(1, regB);
  writeA(0, regA);                        // compiler inserts counted vmcnt for regA
  asm volatile("s_waitcnt vmcnt(4)" ::: "memory");   // stageB(0) landed; loadA(1) in flight
  asm volatile("s_waitcnt lgkmcnt(0)" ::: "memory");
  __builtin_amdgcn_s_barrier();

  // steady: iters 0..29, manually 2-unrolled for static reg-set names
  // iter(ks, CUR, REGW=A(ks+1), REGL<-A(ks+2)):
  //   stageB(ks+1 -> LDS[CUR^1]); loadA(ks+2 -> REGL); compute(LDS[CUR]);
  //   writeA(REGW -> LDS[CUR^1]); vmcnt(4); lgkm(0); barrier
  for (int ks = 0; ks < 30; ks += 2) {
    {
      stageB(1, ks + 1);
      loadA(ks + 2, regA);
      compute(0);
      writeA(1, regB);
      asm volatile("s_waitcnt vmcnt(4)" ::: "memory");
      asm volatile("s_waitcnt lgkmcnt(0)" ::: "memory");
      __builtin_amdgcn_s_barrier();
    }
    {
      stageB(0, ks + 2);
      loadA(ks + 3, regB);
      compute(1);
      writeA(0, regA);
      asm volatile("s_waitcnt vmcnt(4)" ::: "memory");
      asm volatile("s_waitcnt lgkmcnt(0)" ::: "memory");
      __builtin_amdgcn_s_barrier();
    }
  }
  // iter 30: stage 31, no more A-loads
  {
    stageB(1, 31);
    compute(0);
    writeA(1, regB);
    asm volatile("s_waitcnt vmcnt(0)" ::: "memory");
    asm volatile("s_waitcnt lgkmcnt(0)" ::: "memory");
    __builtin_amdgcn_s_barrier();
  }
  // iter 31: final compute
  compute(1);

  // epilogue: RoPE for Q/K columns, transpose-store for V
#pragma unroll
  for (int mt = 0; mt < 2; ++mt) {
    int gm = mb * 64 + wm * 32 + mt * 16 + l16 * 4;
    int bb = gm >> 12, s0 = gm & 4095;
#pragma unroll
    for (int nt = 0; nt < 6; ++nt) {
      int jcol = nb * 192 + wn * 96 + nt * 16 + l15;
      f32x4 v = acc[mt][nt];
      if (jcol < 256) {
        int p = (jcol & 127) >> 1;
        bool even = ((jcol & 1) == 0);
#pragma unroll
        for (int r = 0; r < 4; ++r) {
          float pv = __shfl_xor(v[r], 1);
          int s = s0 + r;
          float cs = cost[s * 64 + p], sn = sint[s * 64 + p];
          float nv = even ? (v[r] * cs - pv * sn) : (v[r] * cs + pv * sn);
          bf16 hb = (bf16)nv;
          if (jcol < 128) Qg[((size_t)(bb << 12) + s) * 128 + jcol] = hb;
          else            Kg[((size_t)(bb << 12) + s) * 128 + jcol - 128] = hb;
        }
      } else {
        int d = jcol - 256;
        union { bf16 h[4]; uint32x2 u; } pk;
#pragma unroll
        for (int r = 0; r < 4; ++r) pk.h[r] = (bf16)v[r];
        *(uint32x2*)((uint8_t*)Vtg + (((size_t)(bb << 7) + d) * 4096 + s0) * 2) = pk.u;
      }
    }
  }
}

// ---------------- flash attention partials (KV-chunked causal) ----------------
// grid: 320 blocks = 4 batches x {j(0..31) x chunks(1+j/8)}; block = 4 waves x 32 q-rows
__global__ __launch_bounds__(256, 2) void k_attn(
    const bf16* __restrict__ Qg, const bf16* __restrict__ Kg, const bf16* __restrict__ Vtg,
    float* __restrict__ PO, float* __restrict__ ML) {
  __shared__ __align__(16) uint8_t smem[81920];  // [2] x (K 16K | V 16K) + 4 x P 4K
  const int tid = threadIdx.x;
  const int lane = tid & 63, w = tid >> 6;
  const int l15 = lane & 15, l16 = lane >> 4;

  int gid = blockIdx.x;
  int b = gid / 80, rr = gid % 80;
  int j, c;
  if (rr < 8)       { j = rr;                 c = 0; }
  else if (rr < 24) { j = 8 + ((rr - 8) >> 1);  c = (rr - 8) & 1; }
  else if (rr < 48) { j = 16 + (rr - 24) / 3;   c = (rr - 24) % 3; }
  else              { j = 24 + ((rr - 48) >> 2); c = (rr - 48) & 3; }

  const int q0w = j * 128 + w * 32;
  const int kv_lo = c * 1024;
  const int kv_hi = min((c + 1) * 1024, (j + 1) * 128);
  const int T = (kv_hi - kv_lo) >> 6;

  bf16x8 qf[2][4];
#pragma unroll
  for (int qt = 0; qt < 2; ++qt)
#pragma unroll
    for (int kk = 0; kk < 4; ++kk)
      qf[qt][kk] = *(const bf16x8*)(Qg + ((size_t)(b << 12) + q0w + qt * 16 + l15) * 128 + kk * 32 + l16 * 8);

  f32x4 o[2][8] = {};
  float m_r[2] = {-1e30f, -1e30f};
  float l_r[2] = {0.f, 0.f};
  uint8_t* pb = smem + 65536 + w * 4096;

  auto stage = [&](int t) {
    uint8_t* kb = smem + (t & 1) * 32768;
    uint8_t* vb = kb + 16384;
    int kv0 = kv_lo + t * 64;
#pragma unroll
    for (int i = 0; i < 4; ++i) {
      int L = i * 4096 + tid * 16;
      {
        int kv = L >> 8, cp = (L >> 4) & 15, cc = cp ^ (kv & 7);
        const uint8_t* src = (const uint8_t*)Kg + ((size_t)((b << 12) + kv0 + kv) << 8) + (cc << 4);
        gload16(src, kb + i * 4096 + w * 1024);
      }
      {
        int d = L >> 7, cp = (L >> 4) & 7, cc = cp ^ (d & 7);
        const uint8_t* src = (const uint8_t*)Vtg + ((size_t)(((b << 7) + d) << 12) + kv0 + (cc << 3)) * 2;
        gload16(src, vb + i * 4096 + w * 1024);
      }
    }
  };

  stage(0);
  __syncthreads();

  for (int t = 0; t < T; ++t) {
    if (t + 1 < T) stage(t + 1);
    const int kv0 = kv_lo + t * 64;
    if (kv0 <= q0w + 31) {
      uint8_t* kb = smem + (t & 1) * 32768;
      uint8_t* vb = kb + 16384;
      f32x4 sfr[4][2] = {};
#pragma unroll
      for (int kk = 0; kk < 4; ++kk) {
#pragma unroll
        for (int kvt = 0; kvt < 4; ++kvt) {
          int kvl = kvt * 16 + l15;
          bf16x8 kf = *(const bf16x8*)(kb + (kvl << 8) + (((kk * 4 + l16) ^ (kvl & 7)) << 4));
#pragma unroll
          for (int qt = 0; qt < 2; ++qt)
            sfr[kvt][qt] = mfma16(kf, qf[qt][kk], sfr[kvt][qt]);
        }
      }
      const bool need_mask = (kv0 + 63 > q0w);
      const float scale = 0.08838834764831845f;
#pragma unroll
      for (int qt = 0; qt < 2; ++qt) {
        const int q = q0w + qt * 16 + l15;
        float pvv[4][4];
        float tmax = -1e30f;
#pragma unroll
        for (int kvt = 0; kvt < 4; ++kvt)
#pragma unroll
          for (int r = 0; r < 4; ++r) {
            float sv = sfr[kvt][qt][r] * scale;
            if (need_mask) {
              int kv = kv0 + kvt * 16 + l16 * 4 + r;
              if (kv > q) sv = -1e30f;
            }
            pvv[kvt][r] = sv;
            tmax = fmaxf(tmax, sv);
          }
        tmax = fmaxf(tmax, __shfl_xor(tmax, 16));
        tmax = fmaxf(tmax, __shfl_xor(tmax, 32));
        float mnew = fmaxf(m_r[qt], tmax);
        float corr = __expf(m_r[qt] - mnew);
        m_r[qt] = mnew;
        float rs = 0.f;
#pragma unroll
        for (int kvt = 0; kvt < 4; ++kvt)
#pragma unroll
          for (int r = 0; r < 4; ++r) {
            float p = __expf(pvv[kvt][r] - mnew);
            pvv[kvt][r] = p;
            rs += p;
          }
        rs += __shfl_xor(rs, 16);
        rs += __shfl_xor(rs, 32);
        l_r[qt] = l_r[qt] * corr + rs;
        const int qrow = qt * 16 + l15;
#pragma unroll
        for (int kvt = 0; kvt < 4; ++kvt) {
          union { bf16 h[4]; uint32x2 u; } pk;
#pragma unroll
          for (int r = 0; r < 4; ++r) pk.h[r] = (bf16)pvv[kvt][r];
          int kv2 = kvt * 32 + l16 * 8;
          *(uint32x2*)(pb + qrow * 128 + ((((kv2 >> 4) ^ (qrow & 7)) << 4) | (kv2 & 15))) = pk.u;
        }
#pragma unroll
        for (int r = 0; r < 4; ++r) {
          float cr = __shfl(corr, l16 * 4 + r);
#pragma unroll
          for (int dt = 0; dt < 8; ++dt) o[qt][dt][r] *= cr;
        }
      }
      // PV
#pragma unroll
      for (int kvb = 0; kvb < 2; ++kvb) {
        bf16x8 pa[2];
#pragma unroll
        for (int qt = 0; qt < 2; ++qt) {
          int qrow = qt * 16 + l15;
          int kv2 = kvb * 64 + l16 * 16;
          pa[qt] = *(const bf16x8*)(pb + qrow * 128 + (((kv2 >> 4) ^ (qrow & 7)) << 4));
        }
#pragma unroll
        for (int dt = 0; dt < 8; ++dt) {
          int d = dt * 16 + l15;
          bf16x8 vf = *(const bf16x8*)(vb + (d << 7) + (((kvb * 4 + l16) ^ (d & 7)) << 4));
#pragma unroll
          for (int qt = 0; qt < 2; ++qt)
            o[qt][dt] = mfma16(pa[qt], vf, o[qt][dt]);
        }
      }
    }
    __syncthreads();
  }

  float* POb = PO + (size_t)((b * 32 + j) * 4 + c) * 16384;
#pragma unroll
  for (int qt = 0; qt < 2; ++qt)
#pragma unroll
    for (int dt = 0; dt < 8; ++dt)
#pragma unroll
      for (int r = 0; r < 4; ++r)
        POb[(w * 32 + qt * 16 + l16 * 4 + r) * 128 + dt * 16 + l15] = o[qt][dt][r];
  float* MLb = ML + (size_t)((b * 32 + j) * 4 + c) * 256;
  if (l16 == 0) {
#pragma unroll
    for (int qt = 0; qt < 2; ++qt) {
      MLb[w * 32 + qt * 16 + l15] = m_r[qt];
      MLb[128 + w * 32 + qt * 16 + l15] = l_r[qt];
    }
  }
}

// ---------------- combine partials ----------------
__global__ void k_combine(const float* __restrict__ PO, const float* __restrict__ ML,
                          float* __restrict__ out) {
  int blk = blockIdx.x;
  int b = blk >> 5, j = blk & 31;
  int nc = 1 + (j >> 3);
  int t = threadIdx.x;
  int q = t >> 1, half = t & 1;
  const float* MLb = ML + (size_t)(b * 32 + j) * 4 * 256;
  float mv[4], lv[4];
  float ms = -1e30f;
  for (int cc = 0; cc < nc; ++cc) {
    mv[cc] = MLb[cc * 256 + q];
    lv[cc] = MLb[cc * 256 + 128 + q];
    ms = fmaxf(ms, mv[cc]);
  }
  float wgt[4];
  float den = 0.f;
  for (int cc = 0; cc < nc; ++cc) { wgt[cc] = __expf(mv[cc] - ms); den += wgt[cc] * lv[cc]; }
  float inv = 1.f / den;
  const float* POb = PO + (size_t)(b * 32 + j) * 4 * 16384 + q * 128 + half * 64;
  float* ob = out + ((size_t)(b << 12) + j * 128 + q) * 128 + half * 64;
  for (int d = 0; d < 64; d += 4) {
    f32x4 a = {0.f, 0.f, 0.f, 0.f};
    for (int cc = 0; cc < nc; ++cc) {
      f32x4 v = *(const f32x4*)(POb + cc * 16384 + d);
      a += v * wgt[cc];
    }
    a *= inv;
    *(f32x4*)(ob + d) = a;
  }
}

extern "C" void kernel_launch(void* const* d_in, const int* in_sizes, int n_in,
                              void* d_out, int out_size, void* d_ws, size_t ws_size,
                              hipStream_t stream) {
  const float* x = (const float*)d_in[0];
  // d_in[1] = mask (causal; computed analytically)
  const float* sint = (const float*)d_in[2];
  const float* cost = (const float*)d_in[3];
  const float* Wq = (const float*)d_in[4];
  const float* Wk = (const float*)d_in[5];
  const float* Wv = (const float*)d_in[6];
  uint8_t* ws = (uint8_t*)d_ws;

  bf16* Wct = (bf16*)(ws + 0x0);        // 1.5 MB
  bf16* Qg  = (bf16*)(ws + 0x180000);   // 4 MB
  bf16* Kg  = (bf16*)(ws + 0x580000);   // 4 MB
  bf16* Vtg = (bf16*)(ws + 0x980000);   // 4 MB
  float* PO = (float*)(ws + 0xD80000);  // 32 MB
  float* ML = (float*)(ws + 0x2D80000); // 0.5 MB
  float* out = (float*)d_out;

  hipLaunchKernelGGL(k_prep, dim3(192), dim3(256), 0, stream, Wq, Wk, Wv, Wct);
  hipLaunchKernelGGL(k_proj, dim3(512), dim3(256), 0, stream, x, sint, cost, Wct, Qg, Kg, Vtg);
  hipLaunchKernelGGL(k_attn, dim3(320), dim3(256), 0, stream, Qg, Kg, Vtg, PO, ML);
  hipLaunchKernelGGL(k_combine, dim3(128), dim3(256), 0, stream, PO, ML, out);
}

// Round 6
// 130.085 us; speedup vs baseline: 1.3613x; 1.0162x over previous
//
#include <hip/hip_runtime.h>
#include <stdint.h>
#include <stddef.h>

typedef __bf16 bf16;
typedef __bf16 bf16x8 __attribute__((ext_vector_type(8)));
typedef float f32x4 __attribute__((ext_vector_type(4)));
typedef unsigned int uint32x2 __attribute__((ext_vector_type(2)));
typedef unsigned int uint32x4 __attribute__((ext_vector_type(4)));

typedef const __attribute__((address_space(1))) uint32_t GU32;
typedef __attribute__((address_space(3))) uint32_t LU32;

__device__ __forceinline__ f32x4 mfma16(bf16x8 a, bf16x8 b, f32x4 c) {
  return __builtin_amdgcn_mfma_f32_16x16x32_bf16(a, b, c, 0, 0, 0);
}
__device__ __forceinline__ void gload16(const void* g, void* l) {
  __builtin_amdgcn_global_load_lds((GU32*)g, (LU32*)l, 16, 0, 0);
}

// ---------------- prep: W_Q|W_K|W_V (f32 [2048][128]) -> Wct bf16 [384][2048] ----
// Coalesced via 64x64 LDS transpose tiles. Grid 192 = 3 matrices x 32 k-tiles x 2 n-tiles.
__global__ __launch_bounds__(256) void k_prep(const float* __restrict__ Wq,
                                              const float* __restrict__ Wk,
                                              const float* __restrict__ Wv,
                                              bf16* __restrict__ Wct) {
  __shared__ float tile[64][65];
  const int tid = threadIdx.x;
  const int widx = blockIdx.x >> 6, rem = blockIdx.x & 63;
  const int k0 = (rem >> 1) * 64, n0 = (rem & 1) * 64;
  const float* W = (widx == 0) ? Wq : (widx == 1) ? Wk : Wv;
  const int rg = tid >> 4, cq = tid & 15;
#pragma unroll
  for (int i = 0; i < 4; ++i) {
    int krow = i * 16 + rg;
    f32x4 v = *(const f32x4*)(W + (size_t)(k0 + krow) * 128 + n0 + cq * 4);
#pragma unroll
    for (int j = 0; j < 4; ++j) tile[krow][cq * 4 + j] = v[j];
  }
  __syncthreads();
#pragma unroll
  for (int i = 0; i < 4; ++i) {
    int nrow = i * 16 + rg;
    union { bf16 h[4]; uint32x2 u; } pk;
#pragma unroll
    for (int j = 0; j < 4; ++j) pk.h[j] = (bf16)tile[cq * 4 + j][nrow];
    *(uint32x2*)(Wct + (size_t)(widx * 128 + n0 + nrow) * 2048 + k0 + cq * 4) = pk.u;
  }
}

// ---------------- projection GEMM + RoPE epilogue ----------------
// x f32 [16384][2048] @ Wct^T -> Q,K (RoPE, bf16 [b][s][128]) and Vt (bf16 [b][128][4096])
// SINGLE N-pass: BM=64, BN=384 (all of Q|K|V). Grid 256, 512 threads (8 waves, 1x8).
// x is read exactly once logically. Counted-vmcnt pipeline, vmcnt(2) steady state.
__global__ __launch_bounds__(512, 1) void k_proj(
    const float* __restrict__ x, const float* __restrict__ sint, const float* __restrict__ cost,
    const bf16* __restrict__ Wct, bf16* __restrict__ Qg, bf16* __restrict__ Kg,
    bf16* __restrict__ Vtg) {
  __shared__ __align__(16) uint8_t smem[114688];  // A 2x8KB @0 | B 2x48KB @16K, swizzled bf16
  const int tid = threadIdx.x;
  const int lane = tid & 63, w = tid >> 6;
  const int l15 = lane & 15, l16 = lane >> 4;
  const int mb = blockIdx.x;
  const int arow = tid >> 3, aj = tid & 7;   // A staging: row 0..63, 8-float chunk 0..7

  f32x4 acc[4][3] = {};
  f32x4 regA[2], regB[2];

  const float* abase = x + (size_t)(mb * 64 + arow) * 2048 + aj * 8;

  auto stageB = [&](int buf, int ks) {
    uint8_t* bbm = smem + 16384 + buf * 49152;
    int k0 = ks * 64;
#pragma unroll
    for (int i = 0; i < 6; ++i) {
      int L = i * 8192 + tid * 16;
      int n = L >> 7, cp = (L >> 4) & 7;
      int cc = cp ^ (n & 7);
      const uint8_t* src = (const uint8_t*)Wct + (((size_t)n * 2048 + k0 + cc * 8) << 1);
      gload16(src, bbm + i * 8192 + w * 1024);
    }
  };
  auto loadA = [&](int ks, f32x4* r) {
    const f32x4* p = (const f32x4*)(abase + ks * 64);
    r[0] = p[0];
    r[1] = p[1];
  };
  auto writeA = [&](int buf, const f32x4* r) {
    uint8_t* ab = smem + buf * 8192;
    union { bf16 v[8]; uint32x4 u; } pk;
#pragma unroll
    for (int e = 0; e < 8; ++e) pk.v[e] = (bf16)r[e >> 2][e & 3];
    *(uint32x4*)(ab + arow * 128 + (((aj ^ (arow & 7)) & 7) << 4)) = pk.u;
  };
  auto compute = [&](int buf) {
    uint8_t* ab = smem + buf * 8192;
    uint8_t* bbm = smem + 16384 + buf * 49152;
    bf16x8 af[2][4], bv[2][3];
#pragma unroll
    for (int kk = 0; kk < 2; ++kk) {
#pragma unroll
      for (int mt = 0; mt < 4; ++mt) {
        int ml = mt * 16 + l15;
        af[kk][mt] = *(const bf16x8*)(ab + ml * 128 + (((kk * 4 + l16) ^ (ml & 7)) << 4));
      }
#pragma unroll
      for (int nt = 0; nt < 3; ++nt) {
        int nl = w * 48 + nt * 16 + l15;
        bv[kk][nt] = *(const bf16x8*)(bbm + nl * 128 + (((kk * 4 + l16) ^ (nl & 7)) << 4));
      }
    }
    __builtin_amdgcn_s_setprio(1);
#pragma unroll
    for (int kk = 0; kk < 2; ++kk)
#pragma unroll
      for (int mt = 0; mt < 4; ++mt)
#pragma unroll
        for (int nt = 0; nt < 3; ++nt)
          acc[mt][nt] = mfma16(af[kk][mt], bv[kk][nt], acc[mt][nt]);
    __builtin_amdgcn_s_setprio(0);
  };

  // prologue: LDS[0] <- B(0), A(0); regB <- A(1) stays in flight
  loadA(0, regA);
  stageB(0, 0);
  loadA(1, regB);
  writeA(0, regA);
  asm volatile("s_waitcnt vmcnt(2)" ::: "memory");   // B(0) landed; A(1) in flight
  asm volatile("s_waitcnt lgkmcnt(0)" ::: "memory");
  __builtin_amdgcn_s_barrier();

  for (int ks = 0; ks < 30; ks += 2) {
    {
      stageB(1, ks + 1);
      loadA(ks + 2, regA);
      compute(0);
      writeA(1, regB);
      asm volatile("s_waitcnt vmcnt(2)" ::: "memory");
      asm volatile("s_waitcnt lgkmcnt(0)" ::: "memory");
      __builtin_amdgcn_s_barrier();
    }
    {
      stageB(0, ks + 2);
      loadA(ks + 3, regB);
      compute(1);
      writeA(0, regA);
      asm volatile("s_waitcnt vmcnt(2)" ::: "memory");
      asm volatile("s_waitcnt lgkmcnt(0)" ::: "memory");
      __builtin_amdgcn_s_barrier();
    }
  }
  {
    stageB(1, 31);
    compute(0);
    writeA(1, regB);
    asm volatile("s_waitcnt vmcnt(0)" ::: "memory");
    asm volatile("s_waitcnt lgkmcnt(0)" ::: "memory");
    __builtin_amdgcn_s_barrier();
  }
  compute(1);

  // epilogue: RoPE for Q/K columns, transpose-store for V
  const int bb = mb >> 6;
#pragma unroll
  for (int mt = 0; mt < 4; ++mt) {
    int gm = mb * 64 + mt * 16 + l16 * 4;
    int s0 = gm & 4095;
#pragma unroll
    for (int nt = 0; nt < 3; ++nt) {
      int jcol = w * 48 + nt * 16 + l15;
      f32x4 v = acc[mt][nt];
      if (jcol < 256) {
        int p = (jcol & 127) >> 1;
        bool even = ((jcol & 1) == 0);
#pragma unroll
        for (int r = 0; r < 4; ++r) {
          float pv = __shfl_xor(v[r], 1);
          int s = s0 + r;
          float cs = cost[s * 64 + p], sn = sint[s * 64 + p];
          float nv = even ? (v[r] * cs - pv * sn) : (v[r] * cs + pv * sn);
          bf16 hb = (bf16)nv;
          if (jcol < 128) Qg[((size_t)(bb << 12) + s) * 128 + jcol] = hb;
          else            Kg[((size_t)(bb << 12) + s) * 128 + jcol - 128] = hb;
        }
      } else {
        int d = jcol - 256;
        union { bf16 h[4]; uint32x2 u; } pk;
#pragma unroll
        for (int r = 0; r < 4; ++r) pk.h[r] = (bf16)v[r];
        *(uint32x2*)((uint8_t*)Vtg + (((size_t)(bb << 7) + d) * 4096 + s0) * 2) = pk.u;
      }
    }
  }
}

// ---------------- flash attention partials (KV-chunked causal) ----------------
// grid: 320 blocks = 4 batches x {j(0..31) x chunks(1+j/8)}; block = 4 waves x 32 q-rows
__global__ __launch_bounds__(256, 2) void k_attn(
    const bf16* __restrict__ Qg, const bf16* __restrict__ Kg, const bf16* __restrict__ Vtg,
    float* __restrict__ PO, float* __restrict__ ML) {
  __shared__ __align__(16) uint8_t smem[81920];  // [2] x (K 16K | V 16K) + 4 x P 4K
  const int tid = threadIdx.x;
  const int lane = tid & 63, w = tid >> 6;
  const int l15 = lane & 15, l16 = lane >> 4;

  int gid = blockIdx.x;
  int b = gid / 80, rr = gid % 80;
  int j, c;
  if (rr < 8)       { j = rr;                 c = 0; }
  else if (rr < 24) { j = 8 + ((rr - 8) >> 1);  c = (rr - 8) & 1; }
  else if (rr < 48) { j = 16 + (rr - 24) / 3;   c = (rr - 24) % 3; }
  else              { j = 24 + ((rr - 48) >> 2); c = (rr - 48) & 3; }

  const int q0w = j * 128 + w * 32;
  const int kv_lo = c * 1024;
  const int kv_hi = min((c + 1) * 1024, (j + 1) * 128);
  const int T = (kv_hi - kv_lo) >> 6;

  bf16x8 qf[2][4];
#pragma unroll
  for (int qt = 0; qt < 2; ++qt)
#pragma unroll
    for (int kk = 0; kk < 4; ++kk)
      qf[qt][kk] = *(const bf16x8*)(Qg + ((size_t)(b << 12) + q0w + qt * 16 + l15) * 128 + kk * 32 + l16 * 8);

  f32x4 o[2][8] = {};
  float m_r[2] = {-1e30f, -1e30f};
  float l_r[2] = {0.f, 0.f};
  uint8_t* pb = smem + 65536 + w * 4096;

  auto stage = [&](int t) {
    uint8_t* kb = smem + (t & 1) * 32768;
    uint8_t* vb = kb + 16384;
    int kv0 = kv_lo + t * 64;
#pragma unroll
    for (int i = 0; i < 4; ++i) {
      int L = i * 4096 + tid * 16;
      {
        int kv = L >> 8, cp = (L >> 4) & 15, cc = cp ^ (kv & 7);
        const uint8_t* src = (const uint8_t*)Kg + ((size_t)((b << 12) + kv0 + kv) << 8) + (cc << 4);
        gload16(src, kb + i * 4096 + w * 1024);
      }
      {
        int d = L >> 7, cp = (L >> 4) & 7, cc = cp ^ (d & 7);
        const uint8_t* src = (const uint8_t*)Vtg + ((size_t)(((b << 7) + d) << 12) + kv0 + (cc << 3)) * 2;
        gload16(src, vb + i * 4096 + w * 1024);
      }
    }
  };

  stage(0);
  __syncthreads();

  for (int t = 0; t < T; ++t) {
    if (t + 1 < T) stage(t + 1);
    const int kv0 = kv_lo + t * 64;
    if (kv0 <= q0w + 31) {
      uint8_t* kb = smem + (t & 1) * 32768;
      uint8_t* vb = kb + 16384;
      f32x4 sfr[4][2] = {};
#pragma unroll
      for (int kk = 0; kk < 4; ++kk) {
#pragma unroll
        for (int kvt = 0; kvt < 4; ++kvt) {
          int kvl = kvt * 16 + l15;
          bf16x8 kf = *(const bf16x8*)(kb + (kvl << 8) + (((kk * 4 + l16) ^ (kvl & 7)) << 4));
#pragma unroll
          for (int qt = 0; qt < 2; ++qt)
            sfr[kvt][qt] = mfma16(kf, qf[qt][kk], sfr[kvt][qt]);
        }
      }
      const bool need_mask = (kv0 + 63 > q0w);
      const float scale = 0.08838834764831845f;
#pragma unroll
      for (int qt = 0; qt < 2; ++qt) {
        const int q = q0w + qt * 16 + l15;
        float pvv[4][4];
        float tmax = -1e30f;
#pragma unroll
        for (int kvt = 0; kvt < 4; ++kvt)
#pragma unroll
          for (int r = 0; r < 4; ++r) {
            float sv = sfr[kvt][qt][r] * scale;
            if (need_mask) {
              int kv = kv0 + kvt * 16 + l16 * 4 + r;
              if (kv > q) sv = -1e30f;
            }
            pvv[kvt][r] = sv;
            tmax = fmaxf(tmax, sv);
          }
        tmax = fmaxf(tmax, __shfl_xor(tmax, 16));
        tmax = fmaxf(tmax, __shfl_xor(tmax, 32));
        float mnew = fmaxf(m_r[qt], tmax);
        float corr = __expf(m_r[qt] - mnew);
        m_r[qt] = mnew;
        float rs = 0.f;
#pragma unroll
        for (int kvt = 0; kvt < 4; ++kvt)
#pragma unroll
          for (int r = 0; r < 4; ++r) {
            float p = __expf(pvv[kvt][r] - mnew);
            pvv[kvt][r] = p;
            rs += p;
          }
        rs += __shfl_xor(rs, 16);
        rs += __shfl_xor(rs, 32);
        l_r[qt] = l_r[qt] * corr + rs;
        const int qrow = qt * 16 + l15;
#pragma unroll
        for (int kvt = 0; kvt < 4; ++kvt) {
          union { bf16 h[4]; uint32x2 u; } pk;
#pragma unroll
          for (int r = 0; r < 4; ++r) pk.h[r] = (bf16)pvv[kvt][r];
          int kv2 = kvt * 32 + l16 * 8;
          *(uint32x2*)(pb + qrow * 128 + ((((kv2 >> 4) ^ (qrow & 7)) << 4) | (kv2 & 15))) = pk.u;
        }
#pragma unroll
        for (int r = 0; r < 4; ++r) {
          float cr = __shfl(corr, l16 * 4 + r);
#pragma unroll
          for (int dt = 0; dt < 8; ++dt) o[qt][dt][r] *= cr;
        }
      }
      // PV
#pragma unroll
      for (int kvb = 0; kvb < 2; ++kvb) {
        bf16x8 pa[2];
#pragma unroll
        for (int qt = 0; qt < 2; ++qt) {
          int qrow = qt * 16 + l15;
          int kv2 = kvb * 64 + l16 * 16;
          pa[qt] = *(const bf16x8*)(pb + qrow * 128 + (((kv2 >> 4) ^ (qrow & 7)) << 4));
        }
#pragma unroll
        for (int dt = 0; dt < 8; ++dt) {
          int d = dt * 16 + l15;
          bf16x8 vf = *(const bf16x8*)(vb + (d << 7) + (((kvb * 4 + l16) ^ (d & 7)) << 4));
#pragma unroll
          for (int qt = 0; qt < 2; ++qt)
            o[qt][dt] = mfma16(pa[qt], vf, o[qt][dt]);
        }
      }
    }
    __syncthreads();
  }

  float* POb = PO + (size_t)((b * 32 + j) * 4 + c) * 16384;
#pragma unroll
  for (int qt = 0; qt < 2; ++qt)
#pragma unroll
    for (int dt = 0; dt < 8; ++dt)
#pragma unroll
      for (int r = 0; r < 4; ++r)
        POb[(w * 32 + qt * 16 + l16 * 4 + r) * 128 + dt * 16 + l15] = o[qt][dt][r];
  float* MLb = ML + (size_t)((b * 32 + j) * 4 + c) * 256;
  if (l16 == 0) {
#pragma unroll
    for (int qt = 0; qt < 2; ++qt) {
      MLb[w * 32 + qt * 16 + l15] = m_r[qt];
      MLb[128 + w * 32 + qt * 16 + l15] = l_r[qt];
    }
  }
}

// ---------------- combine partials ----------------
__global__ void k_combine(const float* __restrict__ PO, const float* __restrict__ ML,
                          float* __restrict__ out) {
  int blk = blockIdx.x;
  int b = blk >> 5, j = blk & 31;
  int nc = 1 + (j >> 3);
  int t = threadIdx.x;
  int q = t >> 1, half = t & 1;
  const float* MLb = ML + (size_t)(b * 32 + j) * 4 * 256;
  float mv[4], lv[4];
  float ms = -1e30f;
  for (int cc = 0; cc < nc; ++cc) {
    mv[cc] = MLb[cc * 256 + q];
    lv[cc] = MLb[cc * 256 + 128 + q];
    ms = fmaxf(ms, mv[cc]);
  }
  float wgt[4];
  float den = 0.f;
  for (int cc = 0; cc < nc; ++cc) { wgt[cc] = __expf(mv[cc] - ms); den += wgt[cc] * lv[cc]; }
  float inv = 1.f / den;
  const float* POb = PO + (size_t)(b * 32 + j) * 4 * 16384 + q * 128 + half * 64;
  float* ob = out + ((size_t)(b << 12) + j * 128 + q) * 128 + half * 64;
  for (int d = 0; d < 64; d += 4) {
    f32x4 a = {0.f, 0.f, 0.f, 0.f};
    for (int cc = 0; cc < nc; ++cc) {
      f32x4 v = *(const f32x4*)(POb + cc * 16384 + d);
      a += v * wgt[cc];
    }
    a *= inv;
    *(f32x4*)(ob + d) = a;
  }
}

extern "C" void kernel_launch(void* const* d_in, const int* in_sizes, int n_in,
                              void* d_out, int out_size, void* d_ws, size_t ws_size,
                              hipStream_t stream) {
  const float* x = (const float*)d_in[0];
  // d_in[1] = mask (causal; computed analytically)
  const float* sint = (const float*)d_in[2];
  const float* cost = (const float*)d_in[3];
  const float* Wq = (const float*)d_in[4];
  const float* Wk = (const float*)d_in[5];
  const float* Wv = (const float*)d_in[6];
  uint8_t* ws = (uint8_t*)d_ws;

  bf16* Wct = (bf16*)(ws + 0x0);        // 1.5 MB
  bf16* Qg  = (bf16*)(ws + 0x180000);   // 4 MB
  bf16* Kg  = (bf16*)(ws + 0x580000);   // 4 MB
  bf16* Vtg = (bf16*)(ws + 0x980000);   // 4 MB
  float* PO = (float*)(ws + 0xD80000);  // 32 MB
  float* ML = (float*)(ws + 0x2D80000); // 0.5 MB
  float* out = (float*)d_out;

  hipLaunchKernelGGL(k_prep, dim3(192), dim3(256), 0, stream, Wq, Wk, Wv, Wct);
  hipLaunchKernelGGL(k_proj, dim3(256), dim3(512), 0, stream, x, sint, cost, Wct, Qg, Kg, Vtg);
  hipLaunchKernelGGL(k_attn, dim3(320), dim3(256), 0, stream, Qg, Kg, Vtg, PO, ML);
  hipLaunchKernelGGL(k_combine, dim3(128), dim3(256), 0, stream, PO, ML, out);
}